// Round 9
// baseline (1224.584 us; speedup 1.0000x reference)
//
#include <hip/hip_runtime.h>
#include <hip/hip_bf16.h>
#include <cstdint>
#include <cmath>

typedef unsigned long long u64;

// ---------------------------------------------------------------------------
// SparseLinear: out[b, dst[e]] += values[e] * x[b, src[e]]; out += bias
// Round 9: DIAGNOSTIC. Reduce stuck at ~285us across 5 structural rewrites
// (occupancy/MLP/footprint/split-K/inline-asm all exonerated). This round
// runs 4 ablation variants of the reduce (full-size, before the real one,
// partial buffer overwritten by the real reduce afterwards) so the rocprof
// per-dispatch table localizes the stall:
//   nogather: no xt load | noatomic: no LDS atomic | norec: no record stream
//   persist:  identical work, 2048-block persistent grid (block-churn probe)
// Packed edge record: [63:32]=val bits, [31:6]=src, [4:0]=dst&31.
// ---------------------------------------------------------------------------

#define RB        32          // rows per bucket
#define RB_SHIFT  5
#define SPLIT     8           // split-K factor
#define RD_K      8

// K0: detect int64 vs int32 indices; zero bucket cursors.
__global__ void SL_detect_zero_kernel(const uint32_t* __restrict__ raw, int* __restrict__ flag,
                                      int* __restrict__ cursor, int NB) {
    int gid = blockIdx.x * blockDim.x + threadIdx.x;
    if (gid == 0) {
        int is64 = 1;
        for (int i = 1; i < 64; i += 2) {
            if (raw[i] != 0u) { is64 = 0; break; }
        }
        *flag = is64;
    }
    for (int i = gid; i < NB; i += gridDim.x * blockDim.x) cursor[i] = 0;
}

// K1: transpose x (32, N) -> xt (N, 32) in bf16. LDS 32x33 tile.
__global__ void SL_prep_kernel(const float* __restrict__ x, __hip_bfloat16* __restrict__ xt,
                               int N) {
    __shared__ float tile[32][33];
    int n0 = blockIdx.x * 32;
    int tx = threadIdx.x, ty = threadIdx.y;
    int n = n0 + tx;
    if (n < N) tile[tx][ty] = x[(size_t)ty * N + n];
    __syncthreads();
    int n2 = n0 + ty;
    if (n2 < N) xt[(size_t)n2 * 32 + tx] = __float2bfloat16(tile[ty][tx]);
}

// K2: bucket scatter. Per-block LDS histogram + rank, one global atomic per
// (block,bucket) to reserve a contiguous slot range, packed 8B nt-writes.
#define SC_BLOCK 256
#define SC_EPT   32   // 8192 edges per block (rank fits 14 bits)
__global__ __launch_bounds__(SC_BLOCK)
void SL_bucket_scatter_kernel(const int* __restrict__ raw, const int* __restrict__ flag,
                              const float* __restrict__ vals, u64* __restrict__ packed,
                              int* __restrict__ cursor, long long E, int NB, int CAP) {
    extern __shared__ int hist[];   // NB ints
    const int tid = threadIdx.x;
    for (int i = tid; i < NB; i += SC_BLOCK) hist[i] = 0;
    __syncthreads();

    const int is64 = *flag;
    const long long base_e = (long long)blockIdx.x * (SC_BLOCK * SC_EPT);
    const long long* raw64 = (const long long*)raw;

    int rp[SC_EPT];
#pragma unroll
    for (int j = 0; j < SC_EPT; ++j) {
        long long e = base_e + tid + (long long)j * SC_BLOCK;
        int v = -1;
        if (e < E) {
            int d = is64 ? (int)raw64[E + e] : raw[E + e];
            int bkt = d >> RB_SHIFT;
            int rank = atomicAdd(&hist[bkt], 1);
            v = (bkt << 19) | ((d & (RB - 1)) << 14) | rank;
        }
        rp[j] = v;
    }
    __syncthreads();

    for (int i = tid; i < NB; i += SC_BLOCK) {
        int c = hist[i];
        hist[i] = (c > 0) ? atomicAdd(&cursor[i], c) : 0;
    }
    __syncthreads();

#pragma unroll
    for (int j = 0; j < SC_EPT; ++j) {
        if (rp[j] < 0) continue;
        long long e = base_e + tid + (long long)j * SC_BLOCK;
        int bkt  = rp[j] >> 19;
        int drow = (rp[j] >> 14) & (RB - 1);
        int rank = rp[j] & 16383;
        int s = is64 ? (int)raw64[e] : raw[e];
        float v = vals[e];
        int off = hist[bkt] + rank;
        if (off < CAP) {
            u64 rec = ((u64)__float_as_uint(v) << 32) | ((u64)(uint)s << 6) | (u64)drow;
            __builtin_nontemporal_store(rec, &packed[(size_t)bkt * CAP + off]);
        }
    }
}

// ---- templated reduce body: MODE 0=real 1=nogather 2=noatomic 3=norec ----
template<int MODE>
__device__ __forceinline__
void reduce_body(const u64* __restrict__ packed, const int* __restrict__ cursor,
                 const __hip_bfloat16* __restrict__ xt, float* __restrict__ partial,
                 int CAP, int NSLICE, int N) {
    __shared__ float acc[RB][33];
    const int tid  = threadIdx.x;
    const int slot = tid >> 5;        // 0..7
    const int b    = tid & 31;        // batch lane

    for (int sb = blockIdx.x; sb < NSLICE; sb += gridDim.x) {
        __syncthreads();              // acc reuse guard across grid-stride iters
        for (int i = tid; i < RB * 33; i += 256) ((float*)acc)[i] = 0.0f;
        __syncthreads();

        const int bkt = sb >> 3;
        const int sl  = sb & (SPLIT - 1);
        int nE = cursor[bkt];
        if (nE > CAP) nE = CAP;
        const int per   = (nE + SPLIT - 1) / SPLIT;
        const int start = sl * per;
        int end = start + per; if (end > nE) end = nE;
        const u64* pb = packed + (size_t)bkt * CAP;

        float racc = 0.0f;
        for (int base = start + slot * RD_K; base < end; base += 8 * RD_K) {
            u64 p[RD_K];
            if (MODE == 3) {
#pragma unroll
                for (int j = 0; j < RD_K; ++j) {
                    int k = base + j;
                    uint32_t h = (uint32_t)k * 2654435761u;
                    uint32_t s = (uint32_t)(((u64)h * (uint32_t)N) >> 32);  // [0,N)
                    p[j] = (0x3F800000ull << 32) | ((u64)s << 6) | (u64)(k & (RB - 1));
                }
            } else {
#pragma unroll
                for (int j = 0; j < RD_K; ++j) {
                    int k = base + j;
                    p[j] = (k < end) ? pb[k] : 0ULL;   // zero rec adds exact 0
                }
            }
            float xv[RD_K];
#pragma unroll
            for (int j = 0; j < RD_K; ++j) {
                if (MODE == 1) {
                    xv[j] = __uint_as_float((uint32_t)(p[j] & 0xFFFFu) << 16);
                } else {
                    int s = (int)((p[j] >> 6) & 0x3FFFFFFu);
                    xv[j] = __bfloat162float(xt[(size_t)s * 32 + b]);
                }
            }
#pragma unroll
            for (int j = 0; j < RD_K; ++j) {
                float vv = __uint_as_float((uint32_t)(p[j] >> 32));
                if (MODE == 2) racc += vv * xv[j];
                else atomicAdd(&acc[(int)(p[j] & (RB - 1))][b], vv * xv[j]);
            }
        }
        __syncthreads();

        float* pp = partial + ((size_t)sb << 10);     // 1024 floats per slice
        if (MODE == 2) {
            pp[tid] = racc;                            // keep gather live
        } else {
            for (int i = tid; i < RB * 32; i += 256)
                pp[i] = acc[i >> 5][i & 31];           // [r][b], coalesced
        }
    }
}

__global__ __launch_bounds__(256)
void SL_red_real(const u64* __restrict__ packed, const int* __restrict__ cursor,
                 const __hip_bfloat16* __restrict__ xt, float* __restrict__ partial,
                 int CAP, int NSLICE, int N) {
    reduce_body<0>(packed, cursor, xt, partial, CAP, NSLICE, N);
}
__global__ __launch_bounds__(256)
void SL_red_nogather(const u64* __restrict__ packed, const int* __restrict__ cursor,
                     const __hip_bfloat16* __restrict__ xt, float* __restrict__ partial,
                     int CAP, int NSLICE, int N) {
    reduce_body<1>(packed, cursor, xt, partial, CAP, NSLICE, N);
}
__global__ __launch_bounds__(256)
void SL_red_noatomic(const u64* __restrict__ packed, const int* __restrict__ cursor,
                     const __hip_bfloat16* __restrict__ xt, float* __restrict__ partial,
                     int CAP, int NSLICE, int N) {
    reduce_body<2>(packed, cursor, xt, partial, CAP, NSLICE, N);
}
__global__ __launch_bounds__(256)
void SL_red_norec(const u64* __restrict__ packed, const int* __restrict__ cursor,
                  const __hip_bfloat16* __restrict__ xt, float* __restrict__ partial,
                  int CAP, int NSLICE, int N) {
    reduce_body<3>(packed, cursor, xt, partial, CAP, NSLICE, N);
}
__global__ __launch_bounds__(256)
void SL_red_persist(const u64* __restrict__ packed, const int* __restrict__ cursor,
                    const __hip_bfloat16* __restrict__ xt, float* __restrict__ partial,
                    int CAP, int NSLICE, int N) {
    reduce_body<0>(packed, cursor, xt, partial, CAP, NSLICE, N);   // same work, small grid
}

// K3b: combine SPLIT partials per bucket, add bias, transposed store to out.
__global__ __launch_bounds__(256)
void SL_combine_kernel(const float* __restrict__ partial, const float* __restrict__ bias,
                       float* __restrict__ out, int M) {
    __shared__ float acc[RB][33];
    const int bkt = blockIdx.x;
    const int tid = threadIdx.x;
    const float* pp = partial + ((size_t)(bkt * SPLIT) << 10);
    for (int i = tid; i < RB * 32; i += 256) {
        float s = 0.0f;
#pragma unroll
        for (int sl = 0; sl < SPLIT; ++sl) s += pp[(sl << 10) + i];
        acc[i >> 5][i & 31] = s;
    }
    __syncthreads();
    const int row0 = bkt << RB_SHIFT;
    for (int i = tid; i < RB * 32; i += 256) {
        int rr = i & (RB - 1);
        int bb = i >> RB_SHIFT;
        int m  = row0 + rr;
        if (m < M)
            __builtin_nontemporal_store(acc[rr][bb] + bias[m], &out[(size_t)bb * M + m]);
    }
}

// ----------------- tier-2 fallback: direct atomic scatter ------------------

__global__ void SL_zero_kernel(int* __restrict__ p, long long n) {
    long long tid = (long long)blockIdx.x * blockDim.x + threadIdx.x;
    if (tid < n) p[tid] = 0;
}

__global__ void SL_convert_kernel(const int* __restrict__ raw, int* __restrict__ out,
                                  long long n, const int* __restrict__ flag) {
    long long tid = (long long)blockIdx.x * blockDim.x + threadIdx.x;
    if (tid >= n) return;
    const int is64 = *flag;
    out[tid] = is64 ? raw[tid * 2] : raw[tid];
}

__global__ void SL_prep_flat_kernel(const float* __restrict__ x, float* __restrict__ xt, int N) {
    long long tid = (long long)blockIdx.x * blockDim.x + threadIdx.x;
    long long totalN = (long long)N * 32;
    if (tid >= totalN) return;
    int n = (int)(tid >> 5);
    int b = (int)(tid & 31);
    xt[tid] = x[(long long)b * N + n];
}

__global__ void SL_scatter_kernel(const int* __restrict__ src, const int* __restrict__ dst,
                                  const float* __restrict__ vals, const float* __restrict__ xt,
                                  float* __restrict__ out_t, long long E) {
    long long tid = (long long)blockIdx.x * blockDim.x + threadIdx.x;
    long long e = tid >> 3;
    if (e >= E) return;
    int b0 = (int)(tid & 7) * 4;
    int s = src[e];
    int d = dst[e];
    float v = vals[e];
    const float4 xv = *reinterpret_cast<const float4*>(xt + (long long)s * 32 + b0);
    float* op = out_t + (long long)d * 32 + b0;
#if defined(__HIP_DEVICE_COMPILE__)
    unsafeAtomicAdd(op + 0, v * xv.x);
    unsafeAtomicAdd(op + 1, v * xv.y);
    unsafeAtomicAdd(op + 2, v * xv.z);
    unsafeAtomicAdd(op + 3, v * xv.w);
#endif
}

__global__ void SL_finalize_kernel(const float* __restrict__ out_t, const float* __restrict__ bias,
                                   float* __restrict__ out, int M) {
    __shared__ float tile[32][33];
    int m0 = blockIdx.x * 32;
    int tx = threadIdx.x;
    int ty = threadIdx.y;
    int m = m0 + ty;
    if (m < M) tile[ty][tx] = out_t[(long long)m * 32 + tx];
    __syncthreads();
    int mm = m0 + tx;
    if (mm < M) out[(long long)ty * M + mm] = tile[tx][ty] + bias[mm];
}

// ----------------- tier-3 fallback: fully generic ------------------

__global__ void SL_init_out_kernel(const float* __restrict__ bias, float* __restrict__ out,
                                   int M, long long total) {
    long long tid = (long long)blockIdx.x * blockDim.x + threadIdx.x;
    if (tid < total) out[tid] = bias[tid % M];
}

__global__ void SL_scatter_direct_kernel(const int* __restrict__ raw, const int* __restrict__ flag,
                                         const float* __restrict__ vals, const float* __restrict__ x,
                                         float* __restrict__ out, long long E, int N, int M, int B) {
    long long e = (long long)blockIdx.x * blockDim.x + threadIdx.x;
    if (e >= E) return;
    const int is64 = *flag;
    long long s = is64 ? raw[2 * e] : raw[e];
    long long d = is64 ? raw[2 * (E + e)] : raw[E + e];
    float v = vals[e];
    for (int b = 0; b < B; ++b) {
#if defined(__HIP_DEVICE_COMPILE__)
        unsafeAtomicAdd(&out[(long long)b * M + d], v * x[(long long)b * N + s]);
#endif
    }
}

extern "C" void kernel_launch(void* const* d_in, const int* in_sizes, int n_in,
                              void* d_out, int out_size, void* d_ws, size_t ws_size,
                              hipStream_t stream) {
    const float* x       = (const float*)d_in[0];
    const int*   idx_raw = (const int*)d_in[1];
    const float* vals    = (const float*)d_in[2];
    const float* bias    = (const float*)d_in[3];
    float*       out     = (float*)d_out;

    const long long twoE = in_sizes[1];
    const long long E    = twoE / 2;
    const int M = in_sizes[3];
    const int B = out_size / M;
    const int N = in_sizes[0] / B;

    const int NB = (M + RB - 1) >> RB_SHIFT;
    double mean = (double)E / (double)NB;
    int CAP = (int)(mean + 8.0 * sqrt(mean > 1.0 ? mean : 1.0) + 128.0);
    CAP = (CAP + 63) & ~63;
    const int NSLICE = NB * SPLIT;

    const size_t xt_b   = (((size_t)N * 32 * sizeof(__hip_bfloat16)) + 255) & ~(size_t)255;
    const size_t pk_b   = (size_t)NB * (size_t)CAP * sizeof(u64);
    const size_t part_b = (size_t)NSLICE * 1024 * sizeof(float);
    const size_t need0  = xt_b + pk_b + part_b + (size_t)NB * 4 + 64;   // split-K path
    const size_t need2  = ((size_t)(N + M) * 32 + (size_t)twoE + 1) * sizeof(int);

    if (B == 32 && N <= (1 << 26) && NB <= 2047 && ws_size >= need0) {
        char* ws = (char*)d_ws;
        __hip_bfloat16* xt = (__hip_bfloat16*)ws;
        u64*   packed  = (u64*)(ws + xt_b);
        float* partial = (float*)(ws + xt_b + pk_b);
        int*   cursor  = (int*)(ws + xt_b + pk_b + part_b);
        int*   flag    = cursor + NB;

        SL_detect_zero_kernel<<<(NB + 255) / 256, 256, 0, stream>>>(
            (const uint32_t*)idx_raw, flag, cursor, NB);

        dim3 pblk(32, 32);
        SL_prep_kernel<<<(N + 31) / 32, pblk, 0, stream>>>(x, xt, N);

        long long epb = (long long)SC_BLOCK * SC_EPT;
        unsigned sgrid = (unsigned)((E + epb - 1) / epb);
        SL_bucket_scatter_kernel<<<sgrid, SC_BLOCK, NB * sizeof(int), stream>>>(
            idx_raw, flag, vals, packed, cursor, E, NB, CAP);

        // ---- diagnostic ablations (full size; partial overwritten by real) ----
        SL_red_nogather<<<NSLICE, 256, 0, stream>>>(packed, cursor, xt, partial, CAP, NSLICE, N);
        SL_red_noatomic<<<NSLICE, 256, 0, stream>>>(packed, cursor, xt, partial, CAP, NSLICE, N);
        SL_red_norec  <<<NSLICE, 256, 0, stream>>>(packed, cursor, xt, partial, CAP, NSLICE, N);
        int pgrid = NSLICE < 2048 ? NSLICE : 2048;
        SL_red_persist<<<pgrid, 256, 0, stream>>>(packed, cursor, xt, partial, CAP, NSLICE, N);

        // ---- real reduce (defines partial contents) + combine ----
        SL_red_real<<<NSLICE, 256, 0, stream>>>(packed, cursor, xt, partial, CAP, NSLICE, N);
        SL_combine_kernel<<<NB, 256, 0, stream>>>(partial, bias, out, M);
    } else if (B == 32 && ws_size >= need2) {
        float* xtf   = (float*)d_ws;
        float* out_t = xtf + (size_t)N * 32;
        int*   idx32 = (int*)(out_t + (size_t)M * 32);
        int*   flag  = idx32 + twoE;

        SL_detect_zero_kernel<<<1, 256, 0, stream>>>((const uint32_t*)idx_raw, flag, flag, 0);
        SL_convert_kernel<<<(unsigned)((twoE + 255) / 256), 256, 0, stream>>>(
            idx_raw, idx32, twoE, flag);
        long long prep_total = (long long)N * 32;
        SL_prep_flat_kernel<<<(unsigned)((prep_total + 255) / 256), 256, 0, stream>>>(x, xtf, N);
        SL_zero_kernel<<<(unsigned)(((long long)M * 32 + 255) / 256), 256, 0, stream>>>(
            (int*)out_t, (long long)M * 32);
        long long sc_total = E * 8;
        SL_scatter_kernel<<<(unsigned)((sc_total + 255) / 256), 256, 0, stream>>>(
            idx32, idx32 + E, vals, xtf, out_t, E);
        dim3 blk(32, 32);
        SL_finalize_kernel<<<(M + 31) / 32, blk, 0, stream>>>(out_t, bias, out, M);
    } else if (ws_size >= sizeof(int)) {
        int* flag = (int*)d_ws;
        SL_detect_zero_kernel<<<1, 256, 0, stream>>>((const uint32_t*)idx_raw, flag, flag, 0);
        long long total = (long long)B * M;
        SL_init_out_kernel<<<(unsigned)((total + 255) / 256), 256, 0, stream>>>(bias, out, M, total);
        SL_scatter_direct_kernel<<<(unsigned)((E + 255) / 256), 256, 0, stream>>>(
            idx_raw, flag, vals, x, out, E, N, M, B);
    }
}

// Round 10
// 120.078 us; speedup vs baseline: 10.1983x; 10.1983x over previous
//
#include <hip/hip_runtime.h>
#include <hip/hip_bf16.h>
#include <cstdint>
#include <cmath>

typedef unsigned long long u64;

// ---------------------------------------------------------------------------
// SparseLinear: out[b, dst[e]] += values[e] * x[b, src[e]]; out += bias
// Round 10: R9 ablation localized the wall: ds_add_f32 LDS-atomic throughput
// (~0.29 lane-ops/cy/CU; 51.2M per-edge atomics => ~283us floor; gather was
// innocent, noatomic ~12us). This round removes per-edge atomics: reduce
// stages the bucket's records to LDS, counting-sorts them by row (32 bins,
// only ~1 rank atomic per EDGE not per edge*batch), then each slot register-
// accumulates its 4 rows' contiguous ranges and writes each (row,b) once.
// Packed edge record: [63:32]=val bits, [31:6]=src, [4:0]=dst&31.
// ---------------------------------------------------------------------------

#define RB        32          // rows per bucket
#define RB_SHIFT  5
#define SREC_MAX  2048        // max records per bucket stageable in LDS

// K0: detect int64 vs int32 indices; zero bucket cursors.
__global__ void SL_detect_zero_kernel(const uint32_t* __restrict__ raw, int* __restrict__ flag,
                                      int* __restrict__ cursor, int NB) {
    int gid = blockIdx.x * blockDim.x + threadIdx.x;
    if (gid == 0) {
        int is64 = 1;
        for (int i = 1; i < 64; i += 2) {
            if (raw[i] != 0u) { is64 = 0; break; }
        }
        *flag = is64;
    }
    for (int i = gid; i < NB; i += gridDim.x * blockDim.x) cursor[i] = 0;
}

// K1: transpose x (32, N) -> xt (N, 32) in bf16. LDS 32x33 tile.
__global__ void SL_prep_kernel(const float* __restrict__ x, __hip_bfloat16* __restrict__ xt,
                               int N) {
    __shared__ float tile[32][33];
    int n0 = blockIdx.x * 32;
    int tx = threadIdx.x, ty = threadIdx.y;
    int n = n0 + tx;
    if (n < N) tile[tx][ty] = x[(size_t)ty * N + n];
    __syncthreads();
    int n2 = n0 + ty;
    if (n2 < N) xt[(size_t)n2 * 32 + tx] = __float2bfloat16(tile[ty][tx]);
}

// K2: bucket scatter. Per-block LDS histogram + rank, one global atomic per
// (block,bucket) to reserve a contiguous slot range, packed 8B nt-writes.
#define SC_BLOCK 256
#define SC_EPT   32   // 8192 edges per block (rank fits 14 bits)
__global__ __launch_bounds__(SC_BLOCK)
void SL_bucket_scatter_kernel(const int* __restrict__ raw, const int* __restrict__ flag,
                              const float* __restrict__ vals, u64* __restrict__ packed,
                              int* __restrict__ cursor, long long E, int NB, int CAP) {
    extern __shared__ int hist[];   // NB ints
    const int tid = threadIdx.x;
    for (int i = tid; i < NB; i += SC_BLOCK) hist[i] = 0;
    __syncthreads();

    const int is64 = *flag;
    const long long base_e = (long long)blockIdx.x * (SC_BLOCK * SC_EPT);
    const long long* raw64 = (const long long*)raw;

    int rp[SC_EPT];
#pragma unroll
    for (int j = 0; j < SC_EPT; ++j) {
        long long e = base_e + tid + (long long)j * SC_BLOCK;
        int v = -1;
        if (e < E) {
            int d = is64 ? (int)raw64[E + e] : raw[E + e];
            int bkt = d >> RB_SHIFT;
            int rank = atomicAdd(&hist[bkt], 1);
            v = (bkt << 19) | ((d & (RB - 1)) << 14) | rank;
        }
        rp[j] = v;
    }
    __syncthreads();

    for (int i = tid; i < NB; i += SC_BLOCK) {
        int c = hist[i];
        hist[i] = (c > 0) ? atomicAdd(&cursor[i], c) : 0;
    }
    __syncthreads();

#pragma unroll
    for (int j = 0; j < SC_EPT; ++j) {
        if (rp[j] < 0) continue;
        long long e = base_e + tid + (long long)j * SC_BLOCK;
        int bkt  = rp[j] >> 19;
        int drow = (rp[j] >> 14) & (RB - 1);
        int rank = rp[j] & 16383;
        int s = is64 ? (int)raw64[e] : raw[e];
        float v = vals[e];
        int off = hist[bkt] + rank;
        if (off < CAP) {
            u64 rec = ((u64)__float_as_uint(v) << 32) | ((u64)(uint)s << 6) | (u64)drow;
            __builtin_nontemporal_store(rec, &packed[(size_t)bkt * CAP + off]);
        }
    }
}

// K3: atomic-free reduce. One 256-thread block per 32-row bucket.
// Stage records -> LDS counting sort by row -> per-slot register accumulate
// over each row's contiguous range -> single LDS write per (row,b) ->
// transposed coalesced store with bias.
__global__ __launch_bounds__(256)
void SL_sort_reduce_kernel(const u64* __restrict__ packed, const int* __restrict__ cursor,
                           const __hip_bfloat16* __restrict__ xt,
                           const float* __restrict__ bias,
                           float* __restrict__ out, int M, int CAP) {
    __shared__ u64 srec[SREC_MAX];
    __shared__ unsigned short perm[SREC_MAX];
    __shared__ int bins[RB + 1];
    __shared__ float acc[RB][33];

    const int tid  = threadIdx.x;
    const int bkt  = blockIdx.x;
    const int row0 = bkt << RB_SHIFT;
    int nE = cursor[bkt];
    if (nE > CAP) nE = CAP;
    const u64* pb = packed + (size_t)bkt * CAP;

    if (tid < RB + 1) bins[tid] = 0;
    __syncthreads();

    // Stage (coalesced) + per-row rank via 32-counter LDS histogram.
    int rk[SREC_MAX / 256];
    int rw[SREC_MAX / 256];
#pragma unroll
    for (int i = 0; i < SREC_MAX / 256; ++i) {
        int k = tid + i * 256;
        rk[i] = -1; rw[i] = 0;
        if (k < nE) {
            u64 r = pb[k];
            srec[k] = r;
            rw[i] = (int)(r & (RB - 1));
            rk[i] = atomicAdd(&bins[rw[i] + 1], 1);
        }
    }
    __syncthreads();

    // Exclusive prefix over 32 bins (serial, trivial): bins[r] = start of row r.
    if (tid == 0) {
#pragma unroll
        for (int r = 1; r <= RB; ++r) bins[r] += bins[r - 1];
    }
    __syncthreads();

    // Scatter permutation indices into row-sorted order.
#pragma unroll
    for (int i = 0; i < SREC_MAX / 256; ++i) {
        if (rk[i] >= 0) perm[bins[rw[i]] + rk[i]] = (unsigned short)(tid + i * 256);
    }
    __syncthreads();

    // Register accumulation: slot s owns rows 4s..4s+3; lane b owns batch b.
    const int slot = tid >> 5;
    const int b    = tid & 31;
#pragma unroll
    for (int rr = 0; rr < 4; ++rr) {
        const int r  = slot * 4 + rr;
        const int j0 = bins[r];
        const int j1 = bins[r + 1];
        float a0 = 0.0f, a1 = 0.0f, a2 = 0.0f, a3 = 0.0f;
        int j = j0;
        for (; j + 4 <= j1; j += 4) {
            int k0 = perm[j], k1 = perm[j + 1], k2 = perm[j + 2], k3 = perm[j + 3];
            u64 p0 = srec[k0], p1 = srec[k1], p2 = srec[k2], p3 = srec[k3];
            float x0 = __bfloat162float(xt[(size_t)((p0 >> 6) & 0x3FFFFFFu) * 32 + b]);
            float x1 = __bfloat162float(xt[(size_t)((p1 >> 6) & 0x3FFFFFFu) * 32 + b]);
            float x2 = __bfloat162float(xt[(size_t)((p2 >> 6) & 0x3FFFFFFu) * 32 + b]);
            float x3 = __bfloat162float(xt[(size_t)((p3 >> 6) & 0x3FFFFFFu) * 32 + b]);
            a0 += __uint_as_float((uint32_t)(p0 >> 32)) * x0;
            a1 += __uint_as_float((uint32_t)(p1 >> 32)) * x1;
            a2 += __uint_as_float((uint32_t)(p2 >> 32)) * x2;
            a3 += __uint_as_float((uint32_t)(p3 >> 32)) * x3;
        }
        for (; j < j1; ++j) {
            int k = perm[j];
            u64 p = srec[k];
            float xv = __bfloat162float(xt[(size_t)((p >> 6) & 0x3FFFFFFu) * 32 + b]);
            a0 += __uint_as_float((uint32_t)(p >> 32)) * xv;
        }
        acc[r][b] = (a0 + a1) + (a2 + a3);   // unique (r,b) owner: plain write
    }
    __syncthreads();

    // out[b, row0+r] = acc[r][b] + bias[row0+r]; consecutive tid -> consecutive r.
    for (int i = tid; i < RB * 32; i += 256) {
        int rr = i & (RB - 1);
        int bb = i >> RB_SHIFT;
        int m  = row0 + rr;
        if (m < M)
            __builtin_nontemporal_store(acc[rr][bb] + bias[m], &out[(size_t)bb * M + m]);
    }
}

// K3 fallback (CAP > SREC_MAX): atomic bucket reduce (R5 structure).
#define RD_K 8
__global__ __launch_bounds__(256)
void SL_bucket_reduce_kernel(const u64* __restrict__ packed, const int* __restrict__ cursor,
                             const __hip_bfloat16* __restrict__ xt,
                             const float* __restrict__ bias,
                             float* __restrict__ out, int M, int CAP) {
    __shared__ float acc[RB][33];
    const int tid = threadIdx.x;
    for (int i = tid; i < RB * 33; i += 256) ((float*)acc)[i] = 0.0f;
    __syncthreads();

    const int bkt  = blockIdx.x;
    const int row0 = bkt << RB_SHIFT;
    int nE = cursor[bkt];
    if (nE > CAP) nE = CAP;
    const u64* pb = packed + (size_t)bkt * CAP;

    const int slot = tid >> 5;
    const int b    = tid & 31;

    for (int base = slot * RD_K; base < nE; base += 8 * RD_K) {
        u64 p[RD_K];
#pragma unroll
        for (int j = 0; j < RD_K; ++j) {
            int k = base + j;
            p[j] = (k < nE) ? pb[k] : 0ULL;
        }
        float xv[RD_K];
#pragma unroll
        for (int j = 0; j < RD_K; ++j) {
            int s = (int)((p[j] >> 6) & 0x3FFFFFFu);
            xv[j] = __bfloat162float(xt[(size_t)s * 32 + b]);
        }
#pragma unroll
        for (int j = 0; j < RD_K; ++j) {
            float v = __uint_as_float((uint32_t)(p[j] >> 32));
            atomicAdd(&acc[(int)(p[j] & (RB - 1))][b], v * xv[j]);
        }
    }
    __syncthreads();

    for (int i = tid; i < RB * 32; i += 256) {
        int rr = i & (RB - 1);
        int bb = i >> RB_SHIFT;
        int m  = row0 + rr;
        if (m < M)
            __builtin_nontemporal_store(acc[rr][bb] + bias[m], &out[(size_t)bb * M + m]);
    }
}

// ----------------- tier-2 fallback: direct atomic scatter ------------------

__global__ void SL_zero_kernel(int* __restrict__ p, long long n) {
    long long tid = (long long)blockIdx.x * blockDim.x + threadIdx.x;
    if (tid < n) p[tid] = 0;
}

__global__ void SL_convert_kernel(const int* __restrict__ raw, int* __restrict__ out,
                                  long long n, const int* __restrict__ flag) {
    long long tid = (long long)blockIdx.x * blockDim.x + threadIdx.x;
    if (tid >= n) return;
    const int is64 = *flag;
    out[tid] = is64 ? raw[tid * 2] : raw[tid];
}

__global__ void SL_prep_flat_kernel(const float* __restrict__ x, float* __restrict__ xt, int N) {
    long long tid = (long long)blockIdx.x * blockDim.x + threadIdx.x;
    long long totalN = (long long)N * 32;
    if (tid >= totalN) return;
    int n = (int)(tid >> 5);
    int b = (int)(tid & 31);
    xt[tid] = x[(long long)b * N + n];
}

__global__ void SL_scatter_kernel(const int* __restrict__ src, const int* __restrict__ dst,
                                  const float* __restrict__ vals, const float* __restrict__ xt,
                                  float* __restrict__ out_t, long long E) {
    long long tid = (long long)blockIdx.x * blockDim.x + threadIdx.x;
    long long e = tid >> 3;
    if (e >= E) return;
    int b0 = (int)(tid & 7) * 4;
    int s = src[e];
    int d = dst[e];
    float v = vals[e];
    const float4 xv = *reinterpret_cast<const float4*>(xt + (long long)s * 32 + b0);
    float* op = out_t + (long long)d * 32 + b0;
#if defined(__HIP_DEVICE_COMPILE__)
    unsafeAtomicAdd(op + 0, v * xv.x);
    unsafeAtomicAdd(op + 1, v * xv.y);
    unsafeAtomicAdd(op + 2, v * xv.z);
    unsafeAtomicAdd(op + 3, v * xv.w);
#endif
}

__global__ void SL_finalize_kernel(const float* __restrict__ out_t, const float* __restrict__ bias,
                                   float* __restrict__ out, int M) {
    __shared__ float tile[32][33];
    int m0 = blockIdx.x * 32;
    int tx = threadIdx.x;
    int ty = threadIdx.y;
    int m = m0 + ty;
    if (m < M) tile[ty][tx] = out_t[(long long)m * 32 + tx];
    __syncthreads();
    int mm = m0 + tx;
    if (mm < M) out[(long long)ty * M + mm] = tile[tx][ty] + bias[mm];
}

// ----------------- tier-3 fallback: fully generic ------------------

__global__ void SL_init_out_kernel(const float* __restrict__ bias, float* __restrict__ out,
                                   int M, long long total) {
    long long tid = (long long)blockIdx.x * blockDim.x + threadIdx.x;
    if (tid < total) out[tid] = bias[tid % M];
}

__global__ void SL_scatter_direct_kernel(const int* __restrict__ raw, const int* __restrict__ flag,
                                         const float* __restrict__ vals, const float* __restrict__ x,
                                         float* __restrict__ out, long long E, int N, int M, int B) {
    long long e = (long long)blockIdx.x * blockDim.x + threadIdx.x;
    if (e >= E) return;
    const int is64 = *flag;
    long long s = is64 ? raw[2 * e] : raw[e];
    long long d = is64 ? raw[2 * (E + e)] : raw[E + e];
    float v = vals[e];
    for (int b = 0; b < B; ++b) {
#if defined(__HIP_DEVICE_COMPILE__)
        unsafeAtomicAdd(&out[(long long)b * M + d], v * x[(long long)b * N + s]);
#endif
    }
}

extern "C" void kernel_launch(void* const* d_in, const int* in_sizes, int n_in,
                              void* d_out, int out_size, void* d_ws, size_t ws_size,
                              hipStream_t stream) {
    const float* x       = (const float*)d_in[0];
    const int*   idx_raw = (const int*)d_in[1];
    const float* vals    = (const float*)d_in[2];
    const float* bias    = (const float*)d_in[3];
    float*       out     = (float*)d_out;

    const long long twoE = in_sizes[1];
    const long long E    = twoE / 2;
    const int M = in_sizes[3];
    const int B = out_size / M;
    const int N = in_sizes[0] / B;

    const int NB = (M + RB - 1) >> RB_SHIFT;
    double mean = (double)E / (double)NB;
    int CAP = (int)(mean + 8.0 * sqrt(mean > 1.0 ? mean : 1.0) + 128.0);
    CAP = (CAP + 63) & ~63;

    const size_t xt_b  = (((size_t)N * 32 * sizeof(__hip_bfloat16)) + 255) & ~(size_t)255;
    const size_t pk_b  = (size_t)NB * (size_t)CAP * sizeof(u64);
    const size_t need1 = xt_b + pk_b + (size_t)NB * 4 + 64;
    const size_t need2 = ((size_t)(N + M) * 32 + (size_t)twoE + 1) * sizeof(int);

    if (B == 32 && N <= (1 << 26) && NB <= 2047 && ws_size >= need1) {
        char* ws = (char*)d_ws;
        __hip_bfloat16* xt = (__hip_bfloat16*)ws;
        u64* packed = (u64*)(ws + xt_b);
        int* cursor = (int*)(ws + xt_b + pk_b);
        int* flag   = cursor + NB;

        SL_detect_zero_kernel<<<(NB + 255) / 256, 256, 0, stream>>>(
            (const uint32_t*)idx_raw, flag, cursor, NB);

        dim3 pblk(32, 32);
        SL_prep_kernel<<<(N + 31) / 32, pblk, 0, stream>>>(x, xt, N);

        long long epb = (long long)SC_BLOCK * SC_EPT;
        unsigned sgrid = (unsigned)((E + epb - 1) / epb);
        SL_bucket_scatter_kernel<<<sgrid, SC_BLOCK, NB * sizeof(int), stream>>>(
            idx_raw, flag, vals, packed, cursor, E, NB, CAP);

        if (CAP <= SREC_MAX) {
            SL_sort_reduce_kernel<<<NB, 256, 0, stream>>>(
                packed, cursor, xt, bias, out, M, CAP);
        } else {
            SL_bucket_reduce_kernel<<<NB, 256, 0, stream>>>(
                packed, cursor, xt, bias, out, M, CAP);
        }
    } else if (B == 32 && ws_size >= need2) {
        float* xtf   = (float*)d_ws;
        float* out_t = xtf + (size_t)N * 32;
        int*   idx32 = (int*)(out_t + (size_t)M * 32);
        int*   flag  = idx32 + twoE;

        SL_detect_zero_kernel<<<1, 256, 0, stream>>>((const uint32_t*)idx_raw, flag, flag, 0);
        SL_convert_kernel<<<(unsigned)((twoE + 255) / 256), 256, 0, stream>>>(
            idx_raw, idx32, twoE, flag);
        long long prep_total = (long long)N * 32;
        SL_prep_flat_kernel<<<(unsigned)((prep_total + 255) / 256), 256, 0, stream>>>(x, xtf, N);
        SL_zero_kernel<<<(unsigned)(((long long)M * 32 + 255) / 256), 256, 0, stream>>>(
            (int*)out_t, (long long)M * 32);
        long long sc_total = E * 8;
        SL_scatter_kernel<<<(unsigned)((sc_total + 255) / 256), 256, 0, stream>>>(
            idx32, idx32 + E, vals, xtf, out_t, E);
        dim3 blk(32, 32);
        SL_finalize_kernel<<<(M + 31) / 32, blk, 0, stream>>>(out_t, bias, out, M);
    } else if (ws_size >= sizeof(int)) {
        int* flag = (int*)d_ws;
        SL_detect_zero_kernel<<<1, 256, 0, stream>>>((const uint32_t*)idx_raw, flag, flag, 0);
        long long total = (long long)B * M;
        SL_init_out_kernel<<<(unsigned)((total + 255) / 256), 256, 0, stream>>>(bias, out, M, total);
        SL_scatter_direct_kernel<<<(unsigned)((E + 255) / 256), 256, 0, stream>>>(
            idx_raw, flag, vals, x, out, E, N, M, B);
    }
}

// Round 11
// 112.460 us; speedup vs baseline: 10.8890x; 1.0677x over previous
//
#include <hip/hip_runtime.h>
#include <hip/hip_bf16.h>
#include <cstdint>
#include <cmath>

typedef unsigned long long u64;

// ---------------------------------------------------------------------------
// SparseLinear: out[b, dst[e]] += values[e] * x[b, src[e]]; out += bias
// Round 11: scatter re-shaped 256x32 -> 1024x8 (same 8192 edges/block so the
// per-bucket write-run locality is preserved; 4x waves per block, 4x shorter
// serial phases). R10 profile: scatter was 7% occupancy, 196 blocks, latency-
// bound. Reduce stays the R10 atomic-free counting-sort version (the 10x
// lever: 51.2M ds_add_f32 had a ~283us hard floor; register accumulation
// after a 32-bin sort removed it).
// Packed edge record: [63:32]=val bits, [31:6]=src, [4:0]=dst&31.
// ---------------------------------------------------------------------------

#define RB        32          // rows per bucket
#define RB_SHIFT  5
#define SREC_MAX  2048        // max records per bucket stageable in LDS

// K0: detect int64 vs int32 indices; zero bucket cursors.
__global__ void SL_detect_zero_kernel(const uint32_t* __restrict__ raw, int* __restrict__ flag,
                                      int* __restrict__ cursor, int NB) {
    int gid = blockIdx.x * blockDim.x + threadIdx.x;
    if (gid == 0) {
        int is64 = 1;
        for (int i = 1; i < 64; i += 2) {
            if (raw[i] != 0u) { is64 = 0; break; }
        }
        *flag = is64;
    }
    for (int i = gid; i < NB; i += gridDim.x * blockDim.x) cursor[i] = 0;
}

// K1: transpose x (32, N) -> xt (N, 32) in bf16. LDS 32x33 tile.
__global__ void SL_prep_kernel(const float* __restrict__ x, __hip_bfloat16* __restrict__ xt,
                               int N) {
    __shared__ float tile[32][33];
    int n0 = blockIdx.x * 32;
    int tx = threadIdx.x, ty = threadIdx.y;
    int n = n0 + tx;
    if (n < N) tile[tx][ty] = x[(size_t)ty * N + n];
    __syncthreads();
    int n2 = n0 + ty;
    if (n2 < N) xt[(size_t)n2 * 32 + tx] = __float2bfloat16(tile[ty][tx]);
}

// K2: bucket scatter. Per-block LDS histogram + rank, one global atomic per
// (block,bucket) to reserve a contiguous slot range, packed 8B nt-writes.
// 1024 threads x 8 edges = 8192 edges/block (rank fits 14 bits).
#define SC_BLOCK 1024
#define SC_EPT   8
__global__ __launch_bounds__(SC_BLOCK)
void SL_bucket_scatter_kernel(const int* __restrict__ raw, const int* __restrict__ flag,
                              const float* __restrict__ vals, u64* __restrict__ packed,
                              int* __restrict__ cursor, long long E, int NB, int CAP) {
    extern __shared__ int hist[];   // NB ints
    const int tid = threadIdx.x;
    for (int i = tid; i < NB; i += SC_BLOCK) hist[i] = 0;
    __syncthreads();

    const int is64 = *flag;
    const long long base_e = (long long)blockIdx.x * (SC_BLOCK * SC_EPT);
    const long long* raw64 = (const long long*)raw;

    // rp[j]: (bkt<<19) | (drow<<14) | rank   (NB <= 2047, drow<32, rank<8192)
    int rp[SC_EPT];
#pragma unroll
    for (int j = 0; j < SC_EPT; ++j) {
        long long e = base_e + tid + (long long)j * SC_BLOCK;
        int v = -1;
        if (e < E) {
            int d = is64 ? (int)raw64[E + e] : raw[E + e];
            int bkt = d >> RB_SHIFT;
            int rank = atomicAdd(&hist[bkt], 1);
            v = (bkt << 19) | ((d & (RB - 1)) << 14) | rank;
        }
        rp[j] = v;
    }
    __syncthreads();

    // Reserve a contiguous range per touched bucket; hist[] becomes base.
    for (int i = tid; i < NB; i += SC_BLOCK) {
        int c = hist[i];
        hist[i] = (c > 0) ? atomicAdd(&cursor[i], c) : 0;
    }
    __syncthreads();

#pragma unroll
    for (int j = 0; j < SC_EPT; ++j) {
        if (rp[j] < 0) continue;
        long long e = base_e + tid + (long long)j * SC_BLOCK;
        int bkt  = rp[j] >> 19;
        int drow = (rp[j] >> 14) & (RB - 1);
        int rank = rp[j] & 16383;
        int s = is64 ? (int)raw64[e] : raw[e];
        float v = vals[e];
        int off = hist[bkt] + rank;
        if (off < CAP) {
            u64 rec = ((u64)__float_as_uint(v) << 32) | ((u64)(uint)s << 6) | (u64)drow;
            __builtin_nontemporal_store(rec, &packed[(size_t)bkt * CAP + off]);
        }
    }
}

// K3: atomic-free reduce. One 256-thread block per 32-row bucket.
// Stage records -> LDS counting sort by row -> per-slot register accumulate
// over each row's contiguous range -> single LDS write per (row,b) ->
// transposed coalesced store with bias.
__global__ __launch_bounds__(256)
void SL_sort_reduce_kernel(const u64* __restrict__ packed, const int* __restrict__ cursor,
                           const __hip_bfloat16* __restrict__ xt,
                           const float* __restrict__ bias,
                           float* __restrict__ out, int M, int CAP) {
    __shared__ u64 srec[SREC_MAX];
    __shared__ unsigned short perm[SREC_MAX];
    __shared__ int bins[RB + 1];
    __shared__ float acc[RB][33];

    const int tid  = threadIdx.x;
    const int bkt  = blockIdx.x;
    const int row0 = bkt << RB_SHIFT;
    int nE = cursor[bkt];
    if (nE > CAP) nE = CAP;
    const u64* pb = packed + (size_t)bkt * CAP;

    if (tid < RB + 1) bins[tid] = 0;
    __syncthreads();

    // Stage (coalesced) + per-row rank via 32-counter LDS histogram.
    int rk[SREC_MAX / 256];
    int rw[SREC_MAX / 256];
#pragma unroll
    for (int i = 0; i < SREC_MAX / 256; ++i) {
        int k = tid + i * 256;
        rk[i] = -1; rw[i] = 0;
        if (k < nE) {
            u64 r = pb[k];
            srec[k] = r;
            rw[i] = (int)(r & (RB - 1));
            rk[i] = atomicAdd(&bins[rw[i] + 1], 1);
        }
    }
    __syncthreads();

    // Exclusive prefix over 32 bins (serial, trivial): bins[r] = start of row r.
    if (tid == 0) {
#pragma unroll
        for (int r = 1; r <= RB; ++r) bins[r] += bins[r - 1];
    }
    __syncthreads();

    // Scatter permutation indices into row-sorted order.
#pragma unroll
    for (int i = 0; i < SREC_MAX / 256; ++i) {
        if (rk[i] >= 0) perm[bins[rw[i]] + rk[i]] = (unsigned short)(tid + i * 256);
    }
    __syncthreads();

    // Register accumulation: slot s owns rows 4s..4s+3; lane b owns batch b.
    const int slot = tid >> 5;
    const int b    = tid & 31;
#pragma unroll
    for (int rr = 0; rr < 4; ++rr) {
        const int r  = slot * 4 + rr;
        const int j0 = bins[r];
        const int j1 = bins[r + 1];
        float a0 = 0.0f, a1 = 0.0f, a2 = 0.0f, a3 = 0.0f;
        int j = j0;
        for (; j + 4 <= j1; j += 4) {
            int k0 = perm[j], k1 = perm[j + 1], k2 = perm[j + 2], k3 = perm[j + 3];
            u64 p0 = srec[k0], p1 = srec[k1], p2 = srec[k2], p3 = srec[k3];
            float x0 = __bfloat162float(xt[(size_t)((p0 >> 6) & 0x3FFFFFFu) * 32 + b]);
            float x1 = __bfloat162float(xt[(size_t)((p1 >> 6) & 0x3FFFFFFu) * 32 + b]);
            float x2 = __bfloat162float(xt[(size_t)((p2 >> 6) & 0x3FFFFFFu) * 32 + b]);
            float x3 = __bfloat162float(xt[(size_t)((p3 >> 6) & 0x3FFFFFFu) * 32 + b]);
            a0 += __uint_as_float((uint32_t)(p0 >> 32)) * x0;
            a1 += __uint_as_float((uint32_t)(p1 >> 32)) * x1;
            a2 += __uint_as_float((uint32_t)(p2 >> 32)) * x2;
            a3 += __uint_as_float((uint32_t)(p3 >> 32)) * x3;
        }
        for (; j < j1; ++j) {
            int k = perm[j];
            u64 p = srec[k];
            float xv = __bfloat162float(xt[(size_t)((p >> 6) & 0x3FFFFFFu) * 32 + b]);
            a0 += __uint_as_float((uint32_t)(p >> 32)) * xv;
        }
        acc[r][b] = (a0 + a1) + (a2 + a3);   // unique (r,b) owner: plain write
    }
    __syncthreads();

    // out[b, row0+r] = acc[r][b] + bias[row0+r]; consecutive tid -> consecutive r.
    for (int i = tid; i < RB * 32; i += 256) {
        int rr = i & (RB - 1);
        int bb = i >> RB_SHIFT;
        int m  = row0 + rr;
        if (m < M)
            __builtin_nontemporal_store(acc[rr][bb] + bias[m], &out[(size_t)bb * M + m]);
    }
}

// K3 fallback (CAP > SREC_MAX): atomic bucket reduce (R5 structure).
#define RD_K 8
__global__ __launch_bounds__(256)
void SL_bucket_reduce_kernel(const u64* __restrict__ packed, const int* __restrict__ cursor,
                             const __hip_bfloat16* __restrict__ xt,
                             const float* __restrict__ bias,
                             float* __restrict__ out, int M, int CAP) {
    __shared__ float acc[RB][33];
    const int tid = threadIdx.x;
    for (int i = tid; i < RB * 33; i += 256) ((float*)acc)[i] = 0.0f;
    __syncthreads();

    const int bkt  = blockIdx.x;
    const int row0 = bkt << RB_SHIFT;
    int nE = cursor[bkt];
    if (nE > CAP) nE = CAP;
    const u64* pb = packed + (size_t)bkt * CAP;

    const int slot = tid >> 5;
    const int b    = tid & 31;

    for (int base = slot * RD_K; base < nE; base += 8 * RD_K) {
        u64 p[RD_K];
#pragma unroll
        for (int j = 0; j < RD_K; ++j) {
            int k = base + j;
            p[j] = (k < nE) ? pb[k] : 0ULL;
        }
        float xv[RD_K];
#pragma unroll
        for (int j = 0; j < RD_K; ++j) {
            int s = (int)((p[j] >> 6) & 0x3FFFFFFu);
            xv[j] = __bfloat162float(xt[(size_t)s * 32 + b]);
        }
#pragma unroll
        for (int j = 0; j < RD_K; ++j) {
            float v = __uint_as_float((uint32_t)(p[j] >> 32));
            atomicAdd(&acc[(int)(p[j] & (RB - 1))][b], v * xv[j]);
        }
    }
    __syncthreads();

    for (int i = tid; i < RB * 32; i += 256) {
        int rr = i & (RB - 1);
        int bb = i >> RB_SHIFT;
        int m  = row0 + rr;
        if (m < M)
            __builtin_nontemporal_store(acc[rr][bb] + bias[m], &out[(size_t)bb * M + m]);
    }
}

// ----------------- tier-2 fallback: direct atomic scatter ------------------

__global__ void SL_zero_kernel(int* __restrict__ p, long long n) {
    long long tid = (long long)blockIdx.x * blockDim.x + threadIdx.x;
    if (tid < n) p[tid] = 0;
}

__global__ void SL_convert_kernel(const int* __restrict__ raw, int* __restrict__ out,
                                  long long n, const int* __restrict__ flag) {
    long long tid = (long long)blockIdx.x * blockDim.x + threadIdx.x;
    if (tid >= n) return;
    const int is64 = *flag;
    out[tid] = is64 ? raw[tid * 2] : raw[tid];
}

__global__ void SL_prep_flat_kernel(const float* __restrict__ x, float* __restrict__ xt, int N) {
    long long tid = (long long)blockIdx.x * blockDim.x + threadIdx.x;
    long long totalN = (long long)N * 32;
    if (tid >= totalN) return;
    int n = (int)(tid >> 5);
    int b = (int)(tid & 31);
    xt[tid] = x[(long long)b * N + n];
}

__global__ void SL_scatter_kernel(const int* __restrict__ src, const int* __restrict__ dst,
                                  const float* __restrict__ vals, const float* __restrict__ xt,
                                  float* __restrict__ out_t, long long E) {
    long long tid = (long long)blockIdx.x * blockDim.x + threadIdx.x;
    long long e = tid >> 3;
    if (e >= E) return;
    int b0 = (int)(tid & 7) * 4;
    int s = src[e];
    int d = dst[e];
    float v = vals[e];
    const float4 xv = *reinterpret_cast<const float4*>(xt + (long long)s * 32 + b0);
    float* op = out_t + (long long)d * 32 + b0;
#if defined(__HIP_DEVICE_COMPILE__)
    unsafeAtomicAdd(op + 0, v * xv.x);
    unsafeAtomicAdd(op + 1, v * xv.y);
    unsafeAtomicAdd(op + 2, v * xv.z);
    unsafeAtomicAdd(op + 3, v * xv.w);
#endif
}

__global__ void SL_finalize_kernel(const float* __restrict__ out_t, const float* __restrict__ bias,
                                   float* __restrict__ out, int M) {
    __shared__ float tile[32][33];
    int m0 = blockIdx.x * 32;
    int tx = threadIdx.x;
    int ty = threadIdx.y;
    int m = m0 + ty;
    if (m < M) tile[ty][tx] = out_t[(long long)m * 32 + tx];
    __syncthreads();
    int mm = m0 + tx;
    if (mm < M) out[(long long)ty * M + mm] = tile[tx][ty] + bias[mm];
}

// ----------------- tier-3 fallback: fully generic ------------------

__global__ void SL_init_out_kernel(const float* __restrict__ bias, float* __restrict__ out,
                                   int M, long long total) {
    long long tid = (long long)blockIdx.x * blockDim.x + threadIdx.x;
    if (tid < total) out[tid] = bias[tid % M];
}

__global__ void SL_scatter_direct_kernel(const int* __restrict__ raw, const int* __restrict__ flag,
                                         const float* __restrict__ vals, const float* __restrict__ x,
                                         float* __restrict__ out, long long E, int N, int M, int B) {
    long long e = (long long)blockIdx.x * blockDim.x + threadIdx.x;
    if (e >= E) return;
    const int is64 = *flag;
    long long s = is64 ? raw[2 * e] : raw[e];
    long long d = is64 ? raw[2 * (E + e)] : raw[E + e];
    float v = vals[e];
    for (int b = 0; b < B; ++b) {
#if defined(__HIP_DEVICE_COMPILE__)
        unsafeAtomicAdd(&out[(long long)b * M + d], v * x[(long long)b * N + s]);
#endif
    }
}

extern "C" void kernel_launch(void* const* d_in, const int* in_sizes, int n_in,
                              void* d_out, int out_size, void* d_ws, size_t ws_size,
                              hipStream_t stream) {
    const float* x       = (const float*)d_in[0];
    const int*   idx_raw = (const int*)d_in[1];
    const float* vals    = (const float*)d_in[2];
    const float* bias    = (const float*)d_in[3];
    float*       out     = (float*)d_out;

    const long long twoE = in_sizes[1];
    const long long E    = twoE / 2;
    const int M = in_sizes[3];
    const int B = out_size / M;
    const int N = in_sizes[0] / B;

    const int NB = (M + RB - 1) >> RB_SHIFT;
    double mean = (double)E / (double)NB;
    int CAP = (int)(mean + 8.0 * sqrt(mean > 1.0 ? mean : 1.0) + 128.0);
    CAP = (CAP + 63) & ~63;

    const size_t xt_b  = (((size_t)N * 32 * sizeof(__hip_bfloat16)) + 255) & ~(size_t)255;
    const size_t pk_b  = (size_t)NB * (size_t)CAP * sizeof(u64);
    const size_t need1 = xt_b + pk_b + (size_t)NB * 4 + 64;
    const size_t need2 = ((size_t)(N + M) * 32 + (size_t)twoE + 1) * sizeof(int);

    if (B == 32 && N <= (1 << 26) && NB <= 2047 && ws_size >= need1) {
        char* ws = (char*)d_ws;
        __hip_bfloat16* xt = (__hip_bfloat16*)ws;
        u64* packed = (u64*)(ws + xt_b);
        int* cursor = (int*)(ws + xt_b + pk_b);
        int* flag   = cursor + NB;

        SL_detect_zero_kernel<<<(NB + 255) / 256, 256, 0, stream>>>(
            (const uint32_t*)idx_raw, flag, cursor, NB);

        dim3 pblk(32, 32);
        SL_prep_kernel<<<(N + 31) / 32, pblk, 0, stream>>>(x, xt, N);

        long long epb = (long long)SC_BLOCK * SC_EPT;   // 8192 edges per block
        unsigned sgrid = (unsigned)((E + epb - 1) / epb);
        SL_bucket_scatter_kernel<<<sgrid, SC_BLOCK, NB * sizeof(int), stream>>>(
            idx_raw, flag, vals, packed, cursor, E, NB, CAP);

        if (CAP <= SREC_MAX) {
            SL_sort_reduce_kernel<<<NB, 256, 0, stream>>>(
                packed, cursor, xt, bias, out, M, CAP);
        } else {
            SL_bucket_reduce_kernel<<<NB, 256, 0, stream>>>(
                packed, cursor, xt, bias, out, M, CAP);
        }
    } else if (B == 32 && ws_size >= need2) {
        float* xtf   = (float*)d_ws;
        float* out_t = xtf + (size_t)N * 32;
        int*   idx32 = (int*)(out_t + (size_t)M * 32);
        int*   flag  = idx32 + twoE;

        SL_detect_zero_kernel<<<1, 256, 0, stream>>>((const uint32_t*)idx_raw, flag, flag, 0);
        SL_convert_kernel<<<(unsigned)((twoE + 255) / 256), 256, 0, stream>>>(
            idx_raw, idx32, twoE, flag);
        long long prep_total = (long long)N * 32;
        SL_prep_flat_kernel<<<(unsigned)((prep_total + 255) / 256), 256, 0, stream>>>(x, xtf, N);
        SL_zero_kernel<<<(unsigned)(((long long)M * 32 + 255) / 256), 256, 0, stream>>>(
            (int*)out_t, (long long)M * 32);
        long long sc_total = E * 8;
        SL_scatter_kernel<<<(unsigned)((sc_total + 255) / 256), 256, 0, stream>>>(
            idx32, idx32 + E, vals, xtf, out_t, E);
        dim3 blk(32, 32);
        SL_finalize_kernel<<<(M + 31) / 32, blk, 0, stream>>>(out_t, bias, out, M);
    } else if (ws_size >= sizeof(int)) {
        int* flag = (int*)d_ws;
        SL_detect_zero_kernel<<<1, 256, 0, stream>>>((const uint32_t*)idx_raw, flag, flag, 0);
        long long total = (long long)B * M;
        SL_init_out_kernel<<<(unsigned)((total + 255) / 256), 256, 0, stream>>>(bias, out, M, total);
        SL_scatter_direct_kernel<<<(unsigned)((E + 255) / 256), 256, 0, stream>>>(
            idx_raw, flag, vals, x, out, E, N, M, B);
    }
}

// Round 12
// 83.699 us; speedup vs baseline: 14.6309x; 1.3436x over previous
//
#include <hip/hip_runtime.h>
#include <hip/hip_bf16.h>
#include <cstdint>
#include <cmath>

typedef unsigned long long u64;

// ---------------------------------------------------------------------------
// SparseLinear: out[b, dst[e]] += values[e] * x[b, src[e]]; out += bias
// Round 12: scatter writes un-nontemporal'd (R11 counters: nt scattered 8B
// record stores bypassed L2 -> 69MB HBM writes for a 12.8MB payload, 5.4x
// amplification = the scatter wall). Packed now L2-cached; SC_EPT 8->4 gives
// 392 blocks (>256 CUs). Reduce stays the R10 atomic-free counting-sort
// (journal: 51.2M ds_add_f32 had a ~283us floor; sort+register-accum was 10x).
// Packed edge record: [63:32]=val bits, [31:6]=src, [4:0]=dst&31.
// ---------------------------------------------------------------------------

#define RB        32          // rows per bucket
#define RB_SHIFT  5
#define SREC_MAX  2048        // max records per bucket stageable in LDS

// K0: detect int64 vs int32 indices; zero bucket cursors.
__global__ void SL_detect_zero_kernel(const uint32_t* __restrict__ raw, int* __restrict__ flag,
                                      int* __restrict__ cursor, int NB) {
    int gid = blockIdx.x * blockDim.x + threadIdx.x;
    if (gid == 0) {
        int is64 = 1;
        for (int i = 1; i < 64; i += 2) {
            if (raw[i] != 0u) { is64 = 0; break; }
        }
        *flag = is64;
    }
    for (int i = gid; i < NB; i += gridDim.x * blockDim.x) cursor[i] = 0;
}

// K1: transpose x (32, N) -> xt (N, 32) in bf16. LDS 32x33 tile.
__global__ void SL_prep_kernel(const float* __restrict__ x, __hip_bfloat16* __restrict__ xt,
                               int N) {
    __shared__ float tile[32][33];
    int n0 = blockIdx.x * 32;
    int tx = threadIdx.x, ty = threadIdx.y;
    int n = n0 + tx;
    if (n < N) tile[tx][ty] = x[(size_t)ty * N + n];
    __syncthreads();
    int n2 = n0 + ty;
    if (n2 < N) xt[(size_t)n2 * 32 + tx] = __float2bfloat16(tile[ty][tx]);
}

// K2: bucket scatter. Per-block LDS histogram + rank, one global atomic per
// (block,bucket) to reserve a contiguous slot range, packed 8B L2-cached
// writes. 1024 threads x 4 edges = 4096 edges/block (392 blocks at E=1.6M).
#define SC_BLOCK 1024
#define SC_EPT   4
__global__ __launch_bounds__(SC_BLOCK)
void SL_bucket_scatter_kernel(const int* __restrict__ raw, const int* __restrict__ flag,
                              const float* __restrict__ vals, u64* __restrict__ packed,
                              int* __restrict__ cursor, long long E, int NB, int CAP) {
    extern __shared__ int hist[];   // NB ints
    const int tid = threadIdx.x;
    for (int i = tid; i < NB; i += SC_BLOCK) hist[i] = 0;
    __syncthreads();

    const int is64 = *flag;
    const long long base_e = (long long)blockIdx.x * (SC_BLOCK * SC_EPT);
    const long long* raw64 = (const long long*)raw;

    // rp[j]: (bkt<<19) | (drow<<14) | rank   (NB <= 2047, drow<32, rank<4096)
    int rp[SC_EPT];
#pragma unroll
    for (int j = 0; j < SC_EPT; ++j) {
        long long e = base_e + tid + (long long)j * SC_BLOCK;
        int v = -1;
        if (e < E) {
            int d = is64 ? (int)raw64[E + e] : raw[E + e];
            int bkt = d >> RB_SHIFT;
            int rank = atomicAdd(&hist[bkt], 1);
            v = (bkt << 19) | ((d & (RB - 1)) << 14) | rank;
        }
        rp[j] = v;
    }
    __syncthreads();

    // Reserve a contiguous range per touched bucket; hist[] becomes base.
    for (int i = tid; i < NB; i += SC_BLOCK) {
        int c = hist[i];
        hist[i] = (c > 0) ? atomicAdd(&cursor[i], c) : 0;
    }
    __syncthreads();

#pragma unroll
    for (int j = 0; j < SC_EPT; ++j) {
        if (rp[j] < 0) continue;
        long long e = base_e + tid + (long long)j * SC_BLOCK;
        int bkt  = rp[j] >> 19;
        int drow = (rp[j] >> 14) & (RB - 1);
        int rank = rp[j] & 16383;
        int s = is64 ? (int)raw64[e] : raw[e];
        float v = vals[e];
        int off = hist[bkt] + rank;
        if (off < CAP) {
            u64 rec = ((u64)__float_as_uint(v) << 32) | ((u64)(uint)s << 6) | (u64)drow;
            packed[(size_t)bkt * CAP + off] = rec;   // L2-cached: lets scattered
                                                     // 8B writes coalesce in L2
        }
    }
}

// K3: atomic-free reduce. One 256-thread block per 32-row bucket.
// Stage records -> LDS counting sort by row -> per-slot register accumulate
// over each row's contiguous range -> single LDS write per (row,b) ->
// transposed coalesced store with bias.
__global__ __launch_bounds__(256)
void SL_sort_reduce_kernel(const u64* __restrict__ packed, const int* __restrict__ cursor,
                           const __hip_bfloat16* __restrict__ xt,
                           const float* __restrict__ bias,
                           float* __restrict__ out, int M, int CAP) {
    __shared__ u64 srec[SREC_MAX];
    __shared__ unsigned short perm[SREC_MAX];
    __shared__ int bins[RB + 1];
    __shared__ float acc[RB][33];

    const int tid  = threadIdx.x;
    const int bkt  = blockIdx.x;
    const int row0 = bkt << RB_SHIFT;
    int nE = cursor[bkt];
    if (nE > CAP) nE = CAP;
    const u64* pb = packed + (size_t)bkt * CAP;

    if (tid < RB + 1) bins[tid] = 0;
    __syncthreads();

    // Stage (coalesced) + per-row rank via 32-counter LDS histogram.
    int rk[SREC_MAX / 256];
    int rw[SREC_MAX / 256];
#pragma unroll
    for (int i = 0; i < SREC_MAX / 256; ++i) {
        int k = tid + i * 256;
        rk[i] = -1; rw[i] = 0;
        if (k < nE) {
            u64 r = pb[k];
            srec[k] = r;
            rw[i] = (int)(r & (RB - 1));
            rk[i] = atomicAdd(&bins[rw[i] + 1], 1);
        }
    }
    __syncthreads();

    // Exclusive prefix over 32 bins (serial, trivial): bins[r] = start of row r.
    if (tid == 0) {
#pragma unroll
        for (int r = 1; r <= RB; ++r) bins[r] += bins[r - 1];
    }
    __syncthreads();

    // Scatter permutation indices into row-sorted order.
#pragma unroll
    for (int i = 0; i < SREC_MAX / 256; ++i) {
        if (rk[i] >= 0) perm[bins[rw[i]] + rk[i]] = (unsigned short)(tid + i * 256);
    }
    __syncthreads();

    // Register accumulation: slot s owns rows 4s..4s+3; lane b owns batch b.
    const int slot = tid >> 5;
    const int b    = tid & 31;
#pragma unroll
    for (int rr = 0; rr < 4; ++rr) {
        const int r  = slot * 4 + rr;
        const int j0 = bins[r];
        const int j1 = bins[r + 1];
        float a0 = 0.0f, a1 = 0.0f, a2 = 0.0f, a3 = 0.0f;
        int j = j0;
        for (; j + 4 <= j1; j += 4) {
            int k0 = perm[j], k1 = perm[j + 1], k2 = perm[j + 2], k3 = perm[j + 3];
            u64 p0 = srec[k0], p1 = srec[k1], p2 = srec[k2], p3 = srec[k3];
            float x0 = __bfloat162float(xt[(size_t)((p0 >> 6) & 0x3FFFFFFu) * 32 + b]);
            float x1 = __bfloat162float(xt[(size_t)((p1 >> 6) & 0x3FFFFFFu) * 32 + b]);
            float x2 = __bfloat162float(xt[(size_t)((p2 >> 6) & 0x3FFFFFFu) * 32 + b]);
            float x3 = __bfloat162float(xt[(size_t)((p3 >> 6) & 0x3FFFFFFu) * 32 + b]);
            a0 += __uint_as_float((uint32_t)(p0 >> 32)) * x0;
            a1 += __uint_as_float((uint32_t)(p1 >> 32)) * x1;
            a2 += __uint_as_float((uint32_t)(p2 >> 32)) * x2;
            a3 += __uint_as_float((uint32_t)(p3 >> 32)) * x3;
        }
        for (; j < j1; ++j) {
            int k = perm[j];
            u64 p = srec[k];
            float xv = __bfloat162float(xt[(size_t)((p >> 6) & 0x3FFFFFFu) * 32 + b]);
            a0 += __uint_as_float((uint32_t)(p >> 32)) * xv;
        }
        acc[r][b] = (a0 + a1) + (a2 + a3);   // unique (r,b) owner: plain write
    }
    __syncthreads();

    // out[b, row0+r] = acc[r][b] + bias[row0+r]; consecutive tid -> consecutive r.
    for (int i = tid; i < RB * 32; i += 256) {
        int rr = i & (RB - 1);
        int bb = i >> RB_SHIFT;
        int m  = row0 + rr;
        if (m < M)
            __builtin_nontemporal_store(acc[rr][bb] + bias[m], &out[(size_t)bb * M + m]);
    }
}

// K3 fallback (CAP > SREC_MAX): atomic bucket reduce (R5 structure).
#define RD_K 8
__global__ __launch_bounds__(256)
void SL_bucket_reduce_kernel(const u64* __restrict__ packed, const int* __restrict__ cursor,
                             const __hip_bfloat16* __restrict__ xt,
                             const float* __restrict__ bias,
                             float* __restrict__ out, int M, int CAP) {
    __shared__ float acc[RB][33];
    const int tid = threadIdx.x;
    for (int i = tid; i < RB * 33; i += 256) ((float*)acc)[i] = 0.0f;
    __syncthreads();

    const int bkt  = blockIdx.x;
    const int row0 = bkt << RB_SHIFT;
    int nE = cursor[bkt];
    if (nE > CAP) nE = CAP;
    const u64* pb = packed + (size_t)bkt * CAP;

    const int slot = tid >> 5;
    const int b    = tid & 31;

    for (int base = slot * RD_K; base < nE; base += 8 * RD_K) {
        u64 p[RD_K];
#pragma unroll
        for (int j = 0; j < RD_K; ++j) {
            int k = base + j;
            p[j] = (k < nE) ? pb[k] : 0ULL;
        }
        float xv[RD_K];
#pragma unroll
        for (int j = 0; j < RD_K; ++j) {
            int s = (int)((p[j] >> 6) & 0x3FFFFFFu);
            xv[j] = __bfloat162float(xt[(size_t)s * 32 + b]);
        }
#pragma unroll
        for (int j = 0; j < RD_K; ++j) {
            float v = __uint_as_float((uint32_t)(p[j] >> 32));
            atomicAdd(&acc[(int)(p[j] & (RB - 1))][b], v * xv[j]);
        }
    }
    __syncthreads();

    for (int i = tid; i < RB * 32; i += 256) {
        int rr = i & (RB - 1);
        int bb = i >> RB_SHIFT;
        int m  = row0 + rr;
        if (m < M)
            __builtin_nontemporal_store(acc[rr][bb] + bias[m], &out[(size_t)bb * M + m]);
    }
}

// ----------------- tier-2 fallback: direct atomic scatter ------------------

__global__ void SL_zero_kernel(int* __restrict__ p, long long n) {
    long long tid = (long long)blockIdx.x * blockDim.x + threadIdx.x;
    if (tid < n) p[tid] = 0;
}

__global__ void SL_convert_kernel(const int* __restrict__ raw, int* __restrict__ out,
                                  long long n, const int* __restrict__ flag) {
    long long tid = (long long)blockIdx.x * blockDim.x + threadIdx.x;
    if (tid >= n) return;
    const int is64 = *flag;
    out[tid] = is64 ? raw[tid * 2] : raw[tid];
}

__global__ void SL_prep_flat_kernel(const float* __restrict__ x, float* __restrict__ xt, int N) {
    long long tid = (long long)blockIdx.x * blockDim.x + threadIdx.x;
    long long totalN = (long long)N * 32;
    if (tid >= totalN) return;
    int n = (int)(tid >> 5);
    int b = (int)(tid & 31);
    xt[tid] = x[(long long)b * N + n];
}

__global__ void SL_scatter_kernel(const int* __restrict__ src, const int* __restrict__ dst,
                                  const float* __restrict__ vals, const float* __restrict__ xt,
                                  float* __restrict__ out_t, long long E) {
    long long tid = (long long)blockIdx.x * blockDim.x + threadIdx.x;
    long long e = tid >> 3;
    if (e >= E) return;
    int b0 = (int)(tid & 7) * 4;
    int s = src[e];
    int d = dst[e];
    float v = vals[e];
    const float4 xv = *reinterpret_cast<const float4*>(xt + (long long)s * 32 + b0);
    float* op = out_t + (long long)d * 32 + b0;
#if defined(__HIP_DEVICE_COMPILE__)
    unsafeAtomicAdd(op + 0, v * xv.x);
    unsafeAtomicAdd(op + 1, v * xv.y);
    unsafeAtomicAdd(op + 2, v * xv.z);
    unsafeAtomicAdd(op + 3, v * xv.w);
#endif
}

__global__ void SL_finalize_kernel(const float* __restrict__ out_t, const float* __restrict__ bias,
                                   float* __restrict__ out, int M) {
    __shared__ float tile[32][33];
    int m0 = blockIdx.x * 32;
    int tx = threadIdx.x;
    int ty = threadIdx.y;
    int m = m0 + ty;
    if (m < M) tile[ty][tx] = out_t[(long long)m * 32 + tx];
    __syncthreads();
    int mm = m0 + tx;
    if (mm < M) out[(long long)ty * M + mm] = tile[tx][ty] + bias[mm];
}

// ----------------- tier-3 fallback: fully generic ------------------

__global__ void SL_init_out_kernel(const float* __restrict__ bias, float* __restrict__ out,
                                   int M, long long total) {
    long long tid = (long long)blockIdx.x * blockDim.x + threadIdx.x;
    if (tid < total) out[tid] = bias[tid % M];
}

__global__ void SL_scatter_direct_kernel(const int* __restrict__ raw, const int* __restrict__ flag,
                                         const float* __restrict__ vals, const float* __restrict__ x,
                                         float* __restrict__ out, long long E, int N, int M, int B) {
    long long e = (long long)blockIdx.x * blockDim.x + threadIdx.x;
    if (e >= E) return;
    const int is64 = *flag;
    long long s = is64 ? raw[2 * e] : raw[e];
    long long d = is64 ? raw[2 * (E + e)] : raw[E + e];
    float v = vals[e];
    for (int b = 0; b < B; ++b) {
#if defined(__HIP_DEVICE_COMPILE__)
        unsafeAtomicAdd(&out[(long long)b * M + d], v * x[(long long)b * N + s]);
#endif
    }
}

extern "C" void kernel_launch(void* const* d_in, const int* in_sizes, int n_in,
                              void* d_out, int out_size, void* d_ws, size_t ws_size,
                              hipStream_t stream) {
    const float* x       = (const float*)d_in[0];
    const int*   idx_raw = (const int*)d_in[1];
    const float* vals    = (const float*)d_in[2];
    const float* bias    = (const float*)d_in[3];
    float*       out     = (float*)d_out;

    const long long twoE = in_sizes[1];
    const long long E    = twoE / 2;
    const int M = in_sizes[3];
    const int B = out_size / M;
    const int N = in_sizes[0] / B;

    const int NB = (M + RB - 1) >> RB_SHIFT;
    double mean = (double)E / (double)NB;
    int CAP = (int)(mean + 8.0 * sqrt(mean > 1.0 ? mean : 1.0) + 128.0);
    CAP = (CAP + 63) & ~63;

    const size_t xt_b  = (((size_t)N * 32 * sizeof(__hip_bfloat16)) + 255) & ~(size_t)255;
    const size_t pk_b  = (size_t)NB * (size_t)CAP * sizeof(u64);
    const size_t need1 = xt_b + pk_b + (size_t)NB * 4 + 64;
    const size_t need2 = ((size_t)(N + M) * 32 + (size_t)twoE + 1) * sizeof(int);

    if (B == 32 && N <= (1 << 26) && NB <= 2047 && ws_size >= need1) {
        char* ws = (char*)d_ws;
        __hip_bfloat16* xt = (__hip_bfloat16*)ws;
        u64* packed = (u64*)(ws + xt_b);
        int* cursor = (int*)(ws + xt_b + pk_b);
        int* flag   = cursor + NB;

        SL_detect_zero_kernel<<<(NB + 255) / 256, 256, 0, stream>>>(
            (const uint32_t*)idx_raw, flag, cursor, NB);

        dim3 pblk(32, 32);
        SL_prep_kernel<<<(N + 31) / 32, pblk, 0, stream>>>(x, xt, N);

        long long epb = (long long)SC_BLOCK * SC_EPT;   // 4096 edges per block
        unsigned sgrid = (unsigned)((E + epb - 1) / epb);
        SL_bucket_scatter_kernel<<<sgrid, SC_BLOCK, NB * sizeof(int), stream>>>(
            idx_raw, flag, vals, packed, cursor, E, NB, CAP);

        if (CAP <= SREC_MAX) {
            SL_sort_reduce_kernel<<<NB, 256, 0, stream>>>(
                packed, cursor, xt, bias, out, M, CAP);
        } else {
            SL_bucket_reduce_kernel<<<NB, 256, 0, stream>>>(
                packed, cursor, xt, bias, out, M, CAP);
        }
    } else if (B == 32 && ws_size >= need2) {
        float* xtf   = (float*)d_ws;
        float* out_t = xtf + (size_t)N * 32;
        int*   idx32 = (int*)(out_t + (size_t)M * 32);
        int*   flag  = idx32 + twoE;

        SL_detect_zero_kernel<<<1, 256, 0, stream>>>((const uint32_t*)idx_raw, flag, flag, 0);
        SL_convert_kernel<<<(unsigned)((twoE + 255) / 256), 256, 0, stream>>>(
            idx_raw, idx32, twoE, flag);
        long long prep_total = (long long)N * 32;
        SL_prep_flat_kernel<<<(unsigned)((prep_total + 255) / 256), 256, 0, stream>>>(x, xtf, N);
        SL_zero_kernel<<<(unsigned)(((long long)M * 32 + 255) / 256), 256, 0, stream>>>(
            (int*)out_t, (long long)M * 32);
        long long sc_total = E * 8;
        SL_scatter_kernel<<<(unsigned)((sc_total + 255) / 256), 256, 0, stream>>>(
            idx32, idx32 + E, vals, xtf, out_t, E);
        dim3 blk(32, 32);
        SL_finalize_kernel<<<(M + 31) / 32, blk, 0, stream>>>(out_t, bias, out, M);
    } else if (ws_size >= sizeof(int)) {
        int* flag = (int*)d_ws;
        SL_detect_zero_kernel<<<1, 256, 0, stream>>>((const uint32_t*)idx_raw, flag, flag, 0);
        long long total = (long long)B * M;
        SL_init_out_kernel<<<(unsigned)((total + 255) / 256), 256, 0, stream>>>(bias, out, M, total);
        SL_scatter_direct_kernel<<<(unsigned)((E + 255) / 256), 256, 0, stream>>>(
            idx_raw, flag, vals, x, out, E, N, M, B);
    }
}

// Round 13
// 83.405 us; speedup vs baseline: 14.6823x; 1.0035x over previous
//
#include <hip/hip_runtime.h>
#include <hip/hip_bf16.h>
#include <cstdint>
#include <cmath>

typedef unsigned long long u64;

// ---------------------------------------------------------------------------
// SparseLinear: out[b, dst[e]] += values[e] * x[b, src[e]]; out += bias
// Round 13: scatter now writes records in block-sorted bucket order. R12
// counters: 1.6M scattered 8B writes ran at ~36G transactions/s (= L2
// scattered-write ceiling, 8 XCD x 2.4GHz x ~2/cy) with 3.7x line
// amplification (WRITE 47MB vs 12.8MB payload). In-block counting sort
// (rank we already compute + block scan) makes consecutive lanes write
// consecutive per-bucket runs -> ~2.5x fewer transactions, shared lines.
// Reduce stays the R10 atomic-free counting-sort (journal: 51.2M ds_add_f32
// had a ~283us hard floor; sort+register-accum was the 10x lever).
// Packed edge record: [63:32]=val bits, [31:6]=src, [4:0]=dst&31.
// ---------------------------------------------------------------------------

#define RB        32          // rows per bucket
#define RB_SHIFT  5
#define SREC_MAX  2048        // max records per bucket stageable in LDS (reduce)

// K0: detect int64 vs int32 indices; zero bucket cursors.
__global__ void SL_detect_zero_kernel(const uint32_t* __restrict__ raw, int* __restrict__ flag,
                                      int* __restrict__ cursor, int NB) {
    int gid = blockIdx.x * blockDim.x + threadIdx.x;
    if (gid == 0) {
        int is64 = 1;
        for (int i = 1; i < 64; i += 2) {
            if (raw[i] != 0u) { is64 = 0; break; }
        }
        *flag = is64;
    }
    for (int i = gid; i < NB; i += gridDim.x * blockDim.x) cursor[i] = 0;
}

// K1: transpose x (32, N) -> xt (N, 32) in bf16. LDS 32x33 tile.
__global__ void SL_prep_kernel(const float* __restrict__ x, __hip_bfloat16* __restrict__ xt,
                               int N) {
    __shared__ float tile[32][33];
    int n0 = blockIdx.x * 32;
    int tx = threadIdx.x, ty = threadIdx.y;
    int n = n0 + tx;
    if (n < N) tile[tx][ty] = x[(size_t)ty * N + n];
    __syncthreads();
    int n2 = n0 + ty;
    if (n2 < N) xt[(size_t)n2 * 32 + tx] = __float2bfloat16(tile[ty][tx]);
}

// K2: bucket scatter with in-block counting sort.
// Phase 1: per-edge bucket rank via LDS histogram atomics.
// Phase 2: block scan of histogram (binbase) + global range reservation.
// Phase 3: stage records into LDS at sorted position (+u16 bucket tag).
// Phase 4: LDS-sequential -> global writes: consecutive lanes emit
//          consecutive per-bucket runs (coalesced within runs).
#define SC_BLOCK 1024
#define SC_EPT   4
#define SC_EDGES (SC_BLOCK * SC_EPT)   // 4096
__global__ __launch_bounds__(SC_BLOCK)
void SL_bucket_scatter_kernel(const int* __restrict__ raw, const int* __restrict__ flag,
                              const float* __restrict__ vals, u64* __restrict__ packed,
                              int* __restrict__ cursor, long long E, int NB, int CAP) {
    extern __shared__ int lds[];
    int* hist    = lds;                       // NB ints; becomes gbase after phase 2
    int* binbase = hist + NB;                 // NB ints
    int* sums    = binbase + NB;              // SC_BLOCK ints
    unsigned short* bkts = (unsigned short*)(sums + SC_BLOCK);   // SC_EDGES u16
    u64* srec = (u64*)(bkts + SC_EDGES);      // SC_EDGES u64 (8B-aligned: offset even*4)

    const int tid = threadIdx.x;
    for (int i = tid; i < NB; i += SC_BLOCK) hist[i] = 0;
    __syncthreads();

    const int is64 = *flag;
    const long long base_e = (long long)blockIdx.x * SC_EDGES;
    const long long* raw64 = (const long long*)raw;

    // Phase 1 — rp[j]: (bkt<<19) | (drow<<14) | rank  (NB<=2047, rank<4096)
    int rp[SC_EPT];
#pragma unroll
    for (int j = 0; j < SC_EPT; ++j) {
        long long e = base_e + tid + (long long)j * SC_BLOCK;
        int v = -1;
        if (e < E) {
            int d = is64 ? (int)raw64[E + e] : raw[E + e];
            int bkt = d >> RB_SHIFT;
            int rank = atomicAdd(&hist[bkt], 1);
            v = (bkt << 19) | ((d & (RB - 1)) << 14) | rank;
        }
        rp[j] = v;
    }
    __syncthreads();

    // Phase 2 — block-local exclusive scan (binbase) + global reservation.
    const int C = (NB + SC_BLOCK - 1) / SC_BLOCK;    // bins per thread (<=2)
    int lo = tid * C, hi = lo + C;
    if (lo > NB) lo = NB;
    if (hi > NB) hi = NB;
    int s = 0;
    for (int i = lo; i < hi; ++i) s += hist[i];
    sums[tid] = s;
    __syncthreads();
    for (int off = 1; off < SC_BLOCK; off <<= 1) {   // Hillis-Steele inclusive
        int v = (tid >= off) ? sums[tid - off] : 0;
        __syncthreads();
        sums[tid] += v;
        __syncthreads();
    }
    int prefix = (tid > 0) ? sums[tid - 1] : 0;
    for (int i = lo; i < hi; ++i) {
        int c = hist[i];
        binbase[i] = prefix;
        prefix += c;
        hist[i] = (c > 0) ? atomicAdd(&cursor[i], c) : 0;   // hist -> gbase
    }
    __syncthreads();

    // Phase 3 — stage records at sorted positions.
#pragma unroll
    for (int j = 0; j < SC_EPT; ++j) {
        if (rp[j] < 0) continue;
        long long e = base_e + tid + (long long)j * SC_BLOCK;
        int bkt  = rp[j] >> 19;
        int drow = (rp[j] >> 14) & (RB - 1);
        int rank = rp[j] & 16383;
        int s2 = is64 ? (int)raw64[e] : raw[e];
        float v = vals[e];
        int pos = binbase[bkt] + rank;
        srec[pos] = ((u64)__float_as_uint(v) << 32) | ((u64)(uint)s2 << 6) | (u64)drow;
        bkts[pos] = (unsigned short)bkt;
    }
    __syncthreads();

    // Phase 4 — sorted, mostly-contiguous global writes.
    long long rem = E - base_e;
    int total = rem < SC_EDGES ? (int)rem : SC_EDGES;
    for (int i = tid; i < total; i += SC_BLOCK) {
        int bkt   = bkts[i];
        int lrank = i - binbase[bkt];
        int off   = hist[bkt] + lrank;
        if (off < CAP) packed[(size_t)bkt * CAP + off] = srec[i];
    }
}

// K3: atomic-free reduce. One 256-thread block per 32-row bucket.
// Stage records -> LDS counting sort by row -> per-slot register accumulate
// over each row's contiguous range -> single LDS write per (row,b) ->
// transposed coalesced store with bias.
__global__ __launch_bounds__(256)
void SL_sort_reduce_kernel(const u64* __restrict__ packed, const int* __restrict__ cursor,
                           const __hip_bfloat16* __restrict__ xt,
                           const float* __restrict__ bias,
                           float* __restrict__ out, int M, int CAP) {
    __shared__ u64 srec[SREC_MAX];
    __shared__ unsigned short perm[SREC_MAX];
    __shared__ int bins[RB + 1];
    __shared__ float acc[RB][33];

    const int tid  = threadIdx.x;
    const int bkt  = blockIdx.x;
    const int row0 = bkt << RB_SHIFT;
    int nE = cursor[bkt];
    if (nE > CAP) nE = CAP;
    const u64* pb = packed + (size_t)bkt * CAP;

    if (tid < RB + 1) bins[tid] = 0;
    __syncthreads();

    // Stage (coalesced) + per-row rank via 32-counter LDS histogram.
    int rk[SREC_MAX / 256];
    int rw[SREC_MAX / 256];
#pragma unroll
    for (int i = 0; i < SREC_MAX / 256; ++i) {
        int k = tid + i * 256;
        rk[i] = -1; rw[i] = 0;
        if (k < nE) {
            u64 r = pb[k];
            srec[k] = r;
            rw[i] = (int)(r & (RB - 1));
            rk[i] = atomicAdd(&bins[rw[i] + 1], 1);
        }
    }
    __syncthreads();

    // Exclusive prefix over 32 bins (serial, trivial): bins[r] = start of row r.
    if (tid == 0) {
#pragma unroll
        for (int r = 1; r <= RB; ++r) bins[r] += bins[r - 1];
    }
    __syncthreads();

    // Scatter permutation indices into row-sorted order.
#pragma unroll
    for (int i = 0; i < SREC_MAX / 256; ++i) {
        if (rk[i] >= 0) perm[bins[rw[i]] + rk[i]] = (unsigned short)(tid + i * 256);
    }
    __syncthreads();

    // Register accumulation: slot s owns rows 4s..4s+3; lane b owns batch b.
    const int slot = tid >> 5;
    const int b    = tid & 31;
#pragma unroll
    for (int rr = 0; rr < 4; ++rr) {
        const int r  = slot * 4 + rr;
        const int j0 = bins[r];
        const int j1 = bins[r + 1];
        float a0 = 0.0f, a1 = 0.0f, a2 = 0.0f, a3 = 0.0f;
        int j = j0;
        for (; j + 4 <= j1; j += 4) {
            int k0 = perm[j], k1 = perm[j + 1], k2 = perm[j + 2], k3 = perm[j + 3];
            u64 p0 = srec[k0], p1 = srec[k1], p2 = srec[k2], p3 = srec[k3];
            float x0 = __bfloat162float(xt[(size_t)((p0 >> 6) & 0x3FFFFFFu) * 32 + b]);
            float x1 = __bfloat162float(xt[(size_t)((p1 >> 6) & 0x3FFFFFFu) * 32 + b]);
            float x2 = __bfloat162float(xt[(size_t)((p2 >> 6) & 0x3FFFFFFu) * 32 + b]);
            float x3 = __bfloat162float(xt[(size_t)((p3 >> 6) & 0x3FFFFFFu) * 32 + b]);
            a0 += __uint_as_float((uint32_t)(p0 >> 32)) * x0;
            a1 += __uint_as_float((uint32_t)(p1 >> 32)) * x1;
            a2 += __uint_as_float((uint32_t)(p2 >> 32)) * x2;
            a3 += __uint_as_float((uint32_t)(p3 >> 32)) * x3;
        }
        for (; j < j1; ++j) {
            int k = perm[j];
            u64 p = srec[k];
            float xv = __bfloat162float(xt[(size_t)((p >> 6) & 0x3FFFFFFu) * 32 + b]);
            a0 += __uint_as_float((uint32_t)(p >> 32)) * xv;
        }
        acc[r][b] = (a0 + a1) + (a2 + a3);   // unique (r,b) owner: plain write
    }
    __syncthreads();

    // out[b, row0+r] = acc[r][b] + bias[row0+r]; consecutive tid -> consecutive r.
    for (int i = tid; i < RB * 32; i += 256) {
        int rr = i & (RB - 1);
        int bb = i >> RB_SHIFT;
        int m  = row0 + rr;
        if (m < M)
            __builtin_nontemporal_store(acc[rr][bb] + bias[m], &out[(size_t)bb * M + m]);
    }
}

// K3 fallback (CAP > SREC_MAX): atomic bucket reduce (R5 structure).
#define RD_K 8
__global__ __launch_bounds__(256)
void SL_bucket_reduce_kernel(const u64* __restrict__ packed, const int* __restrict__ cursor,
                             const __hip_bfloat16* __restrict__ xt,
                             const float* __restrict__ bias,
                             float* __restrict__ out, int M, int CAP) {
    __shared__ float acc[RB][33];
    const int tid = threadIdx.x;
    for (int i = tid; i < RB * 33; i += 256) ((float*)acc)[i] = 0.0f;
    __syncthreads();

    const int bkt  = blockIdx.x;
    const int row0 = bkt << RB_SHIFT;
    int nE = cursor[bkt];
    if (nE > CAP) nE = CAP;
    const u64* pb = packed + (size_t)bkt * CAP;

    const int slot = tid >> 5;
    const int b    = tid & 31;

    for (int base = slot * RD_K; base < nE; base += 8 * RD_K) {
        u64 p[RD_K];
#pragma unroll
        for (int j = 0; j < RD_K; ++j) {
            int k = base + j;
            p[j] = (k < nE) ? pb[k] : 0ULL;
        }
        float xv[RD_K];
#pragma unroll
        for (int j = 0; j < RD_K; ++j) {
            int s = (int)((p[j] >> 6) & 0x3FFFFFFu);
            xv[j] = __bfloat162float(xt[(size_t)s * 32 + b]);
        }
#pragma unroll
        for (int j = 0; j < RD_K; ++j) {
            float v = __uint_as_float((uint32_t)(p[j] >> 32));
            atomicAdd(&acc[(int)(p[j] & (RB - 1))][b], v * xv[j]);
        }
    }
    __syncthreads();

    for (int i = tid; i < RB * 32; i += 256) {
        int rr = i & (RB - 1);
        int bb = i >> RB_SHIFT;
        int m  = row0 + rr;
        if (m < M)
            __builtin_nontemporal_store(acc[rr][bb] + bias[m], &out[(size_t)bb * M + m]);
    }
}

// ----------------- tier-2 fallback: direct atomic scatter ------------------

__global__ void SL_zero_kernel(int* __restrict__ p, long long n) {
    long long tid = (long long)blockIdx.x * blockDim.x + threadIdx.x;
    if (tid < n) p[tid] = 0;
}

__global__ void SL_convert_kernel(const int* __restrict__ raw, int* __restrict__ out,
                                  long long n, const int* __restrict__ flag) {
    long long tid = (long long)blockIdx.x * blockDim.x + threadIdx.x;
    if (tid >= n) return;
    const int is64 = *flag;
    out[tid] = is64 ? raw[tid * 2] : raw[tid];
}

__global__ void SL_prep_flat_kernel(const float* __restrict__ x, float* __restrict__ xt, int N) {
    long long tid = (long long)blockIdx.x * blockDim.x + threadIdx.x;
    long long totalN = (long long)N * 32;
    if (tid >= totalN) return;
    int n = (int)(tid >> 5);
    int b = (int)(tid & 31);
    xt[tid] = x[(long long)b * N + n];
}

__global__ void SL_scatter_kernel(const int* __restrict__ src, const int* __restrict__ dst,
                                  const float* __restrict__ vals, const float* __restrict__ xt,
                                  float* __restrict__ out_t, long long E) {
    long long tid = (long long)blockIdx.x * blockDim.x + threadIdx.x;
    long long e = tid >> 3;
    if (e >= E) return;
    int b0 = (int)(tid & 7) * 4;
    int s = src[e];
    int d = dst[e];
    float v = vals[e];
    const float4 xv = *reinterpret_cast<const float4*>(xt + (long long)s * 32 + b0);
    float* op = out_t + (long long)d * 32 + b0;
#if defined(__HIP_DEVICE_COMPILE__)
    unsafeAtomicAdd(op + 0, v * xv.x);
    unsafeAtomicAdd(op + 1, v * xv.y);
    unsafeAtomicAdd(op + 2, v * xv.z);
    unsafeAtomicAdd(op + 3, v * xv.w);
#endif
}

__global__ void SL_finalize_kernel(const float* __restrict__ out_t, const float* __restrict__ bias,
                                   float* __restrict__ out, int M) {
    __shared__ float tile[32][33];
    int m0 = blockIdx.x * 32;
    int tx = threadIdx.x;
    int ty = threadIdx.y;
    int m = m0 + ty;
    if (m < M) tile[ty][tx] = out_t[(long long)m * 32 + tx];
    __syncthreads();
    int mm = m0 + tx;
    if (mm < M) out[(long long)ty * M + mm] = tile[tx][ty] + bias[mm];
}

// ----------------- tier-3 fallback: fully generic ------------------

__global__ void SL_init_out_kernel(const float* __restrict__ bias, float* __restrict__ out,
                                   int M, long long total) {
    long long tid = (long long)blockIdx.x * blockDim.x + threadIdx.x;
    if (tid < total) out[tid] = bias[tid % M];
}

__global__ void SL_scatter_direct_kernel(const int* __restrict__ raw, const int* __restrict__ flag,
                                         const float* __restrict__ vals, const float* __restrict__ x,
                                         float* __restrict__ out, long long E, int N, int M, int B) {
    long long e = (long long)blockIdx.x * blockDim.x + threadIdx.x;
    if (e >= E) return;
    const int is64 = *flag;
    long long s = is64 ? raw[2 * e] : raw[e];
    long long d = is64 ? raw[2 * (E + e)] : raw[E + e];
    float v = vals[e];
    for (int b = 0; b < B; ++b) {
#if defined(__HIP_DEVICE_COMPILE__)
        unsafeAtomicAdd(&out[(long long)b * M + d], v * x[(long long)b * N + s]);
#endif
    }
}

extern "C" void kernel_launch(void* const* d_in, const int* in_sizes, int n_in,
                              void* d_out, int out_size, void* d_ws, size_t ws_size,
                              hipStream_t stream) {
    const float* x       = (const float*)d_in[0];
    const int*   idx_raw = (const int*)d_in[1];
    const float* vals    = (const float*)d_in[2];
    const float* bias    = (const float*)d_in[3];
    float*       out     = (float*)d_out;

    const long long twoE = in_sizes[1];
    const long long E    = twoE / 2;
    const int M = in_sizes[3];
    const int B = out_size / M;
    const int N = in_sizes[0] / B;

    const int NB = (M + RB - 1) >> RB_SHIFT;
    double mean = (double)E / (double)NB;
    int CAP = (int)(mean + 8.0 * sqrt(mean > 1.0 ? mean : 1.0) + 128.0);
    CAP = (CAP + 63) & ~63;

    const size_t xt_b  = (((size_t)N * 32 * sizeof(__hip_bfloat16)) + 255) & ~(size_t)255;
    const size_t pk_b  = (size_t)NB * (size_t)CAP * sizeof(u64);
    const size_t need1 = xt_b + pk_b + (size_t)NB * 4 + 64;
    const size_t need2 = ((size_t)(N + M) * 32 + (size_t)twoE + 1) * sizeof(int);

    // Scatter dynamic LDS: hist + binbase (NB ints each) + sums (1024 ints)
    // + bkts (SC_EDGES u16) + srec (SC_EDGES u64).
    const size_t sc_lds = (size_t)(2 * NB + SC_BLOCK) * 4
                        + (size_t)SC_EDGES * 2 + (size_t)SC_EDGES * 8;

    if (B == 32 && N <= (1 << 26) && NB <= 2047 && ws_size >= need1 && sc_lds <= 64 * 1024) {
        char* ws = (char*)d_ws;
        __hip_bfloat16* xt = (__hip_bfloat16*)ws;
        u64* packed = (u64*)(ws + xt_b);
        int* cursor = (int*)(ws + xt_b + pk_b);
        int* flag   = cursor + NB;

        SL_detect_zero_kernel<<<(NB + 255) / 256, 256, 0, stream>>>(
            (const uint32_t*)idx_raw, flag, cursor, NB);

        dim3 pblk(32, 32);
        SL_prep_kernel<<<(N + 31) / 32, pblk, 0, stream>>>(x, xt, N);

        unsigned sgrid = (unsigned)((E + SC_EDGES - 1) / SC_EDGES);
        SL_bucket_scatter_kernel<<<sgrid, SC_BLOCK, (unsigned)sc_lds, stream>>>(
            idx_raw, flag, vals, packed, cursor, E, NB, CAP);

        if (CAP <= SREC_MAX) {
            SL_sort_reduce_kernel<<<NB, 256, 0, stream>>>(
                packed, cursor, xt, bias, out, M, CAP);
        } else {
            SL_bucket_reduce_kernel<<<NB, 256, 0, stream>>>(
                packed, cursor, xt, bias, out, M, CAP);
        }
    } else if (B == 32 && ws_size >= need2) {
        float* xtf   = (float*)d_ws;
        float* out_t = xtf + (size_t)N * 32;
        int*   idx32 = (int*)(out_t + (size_t)M * 32);
        int*   flag  = idx32 + twoE;

        SL_detect_zero_kernel<<<1, 256, 0, stream>>>((const uint32_t*)idx_raw, flag, flag, 0);
        SL_convert_kernel<<<(unsigned)((twoE + 255) / 256), 256, 0, stream>>>(
            idx_raw, idx32, twoE, flag);
        long long prep_total = (long long)N * 32;
        SL_prep_flat_kernel<<<(unsigned)((prep_total + 255) / 256), 256, 0, stream>>>(x, xtf, N);
        SL_zero_kernel<<<(unsigned)(((long long)M * 32 + 255) / 256), 256, 0, stream>>>(
            (int*)out_t, (long long)M * 32);
        long long sc_total = E * 8;
        SL_scatter_kernel<<<(unsigned)((sc_total + 255) / 256), 256, 0, stream>>>(
            idx32, idx32 + E, vals, xtf, out_t, E);
        dim3 blk(32, 32);
        SL_finalize_kernel<<<(M + 31) / 32, blk, 0, stream>>>(out_t, bias, out, M);
    } else if (ws_size >= sizeof(int)) {
        int* flag = (int*)d_ws;
        SL_detect_zero_kernel<<<1, 256, 0, stream>>>((const uint32_t*)idx_raw, flag, flag, 0);
        long long total = (long long)B * M;
        SL_init_out_kernel<<<(unsigned)((total + 255) / 256), 256, 0, stream>>>(bias, out, M, total);
        SL_scatter_direct_kernel<<<(unsigned)((E + 255) / 256), 256, 0, stream>>>(
            idx_raw, flag, vals, x, out, E, N, M, B);
    }
}

// Round 14
// 68.213 us; speedup vs baseline: 17.9524x; 1.2227x over previous
//
#include <hip/hip_runtime.h>
#include <hip/hip_bf16.h>
#include <cstdint>
#include <cmath>

typedef unsigned long long u64;

// ---------------------------------------------------------------------------
// SparseLinear: out[b, dst[e]] += values[e] * x[b, src[e]]; out += bias
// Round 14: overhead-stripping on both hot kernels.
//  Scatter: wave-shfl scan (2 barriers vs R13's 20 Hillis-Steele barriers);
//           src/val cached in registers from phase 1 (no 19MB re-read).
//  Reduce:  records scattered directly into row-sorted LDS (no perm
//           indirection -> 1 LDS broadcast/record) and 512 threads
//           (16 slots x 2 rows: half the serial chain, 2x TLP).
// Journal: 51.2M ds_add_f32 atomics had a ~283us floor (R9 ablation);
// counting-sort + register accumulation is the 10x lever. nt-stores on
// scattered 8B records caused 5.4x HBM write amplification (R11->R12).
// Packed edge record: [63:32]=val bits, [31:6]=src, [4:0]=dst&31.
// ---------------------------------------------------------------------------

#define RB        32          // rows per bucket
#define RB_SHIFT  5
#define SREC_MAX  2048        // max records per bucket stageable in LDS (reduce)

// K0: detect int64 vs int32 indices; zero bucket cursors.
__global__ void SL_detect_zero_kernel(const uint32_t* __restrict__ raw, int* __restrict__ flag,
                                      int* __restrict__ cursor, int NB) {
    int gid = blockIdx.x * blockDim.x + threadIdx.x;
    if (gid == 0) {
        int is64 = 1;
        for (int i = 1; i < 64; i += 2) {
            if (raw[i] != 0u) { is64 = 0; break; }
        }
        *flag = is64;
    }
    for (int i = gid; i < NB; i += gridDim.x * blockDim.x) cursor[i] = 0;
}

// K1: transpose x (32, N) -> xt (N, 32) in bf16. LDS 32x33 tile.
__global__ void SL_prep_kernel(const float* __restrict__ x, __hip_bfloat16* __restrict__ xt,
                               int N) {
    __shared__ float tile[32][33];
    int n0 = blockIdx.x * 32;
    int tx = threadIdx.x, ty = threadIdx.y;
    int n = n0 + tx;
    if (n < N) tile[tx][ty] = x[(size_t)ty * N + n];
    __syncthreads();
    int n2 = n0 + ty;
    if (n2 < N) xt[(size_t)n2 * 32 + tx] = __float2bfloat16(tile[ty][tx]);
}

// K2: bucket scatter with in-block counting sort.
// Phase 1: per-edge bucket rank via LDS histogram atomics; src/val cached
//          in registers (loads overlap the scan).
// Phase 2: wave-shfl scan of histogram (2 barriers total) + global range
//          reservation.
// Phase 3: stage records into LDS at sorted position (+u16 bucket tag).
// Phase 4: LDS-sequential -> global writes (coalesced per-bucket runs).
#define SC_BLOCK 1024
#define SC_EPT   4
#define SC_EDGES (SC_BLOCK * SC_EPT)   // 4096
#define SC_WAVES (SC_BLOCK / 64)       // 16
__global__ __launch_bounds__(SC_BLOCK)
void SL_bucket_scatter_kernel(const int* __restrict__ raw, const int* __restrict__ flag,
                              const float* __restrict__ vals, u64* __restrict__ packed,
                              int* __restrict__ cursor, long long E, int NB, int CAP) {
    extern __shared__ int lds[];
    int* hist    = lds;                       // NB ints; becomes gbase after phase 2
    int* binbase = hist + NB;                 // NB ints
    int* wsum    = binbase + NB;              // SC_WAVES ints (pad to 16)
    unsigned short* bkts = (unsigned short*)(wsum + 16);         // SC_EDGES u16
    u64* srec = (u64*)(bkts + SC_EDGES);      // SC_EDGES u64

    const int tid  = threadIdx.x;
    const int lane = tid & 63;
    const int wid  = tid >> 6;
    for (int i = tid; i < NB; i += SC_BLOCK) hist[i] = 0;
    __syncthreads();

    const int is64 = *flag;
    const long long base_e = (long long)blockIdx.x * SC_EDGES;
    const long long* raw64 = (const long long*)raw;

    // Phase 1 — rank + cache src/val in registers.
    int   rp[SC_EPT];
    int   sv[SC_EPT];
    float vv[SC_EPT];
#pragma unroll
    for (int j = 0; j < SC_EPT; ++j) {
        long long e = base_e + tid + (long long)j * SC_BLOCK;
        int v = -1;
        if (e < E) {
            int d = is64 ? (int)raw64[E + e] : raw[E + e];
            sv[j] = is64 ? (int)raw64[e] : raw[e];
            vv[j] = vals[e];
            int bkt = d >> RB_SHIFT;
            int rank = atomicAdd(&hist[bkt], 1);
            v = (bkt << 19) | rank;           // drow kept via d&31 below
            v |= (d & (RB - 1)) << 14;
        } else { sv[j] = 0; vv[j] = 0.0f; }
        rp[j] = v;
    }
    __syncthreads();

    // Phase 2 — wave-shfl scan (block-exclusive binbase) + global reservation.
    const int C = (NB + SC_BLOCK - 1) / SC_BLOCK;    // bins per thread (<=2)
    int lo = tid * C, hi = lo + C;
    if (lo > NB) lo = NB;
    if (hi > NB) hi = NB;
    int sown = 0;
    for (int i = lo; i < hi; ++i) sown += hist[i];
    int s = sown;
#pragma unroll
    for (int o = 1; o < 64; o <<= 1) {        // wave inclusive scan
        int v = __shfl_up(s, o);
        if (lane >= o) s += v;
    }
    if (lane == 63) wsum[wid] = s;
    __syncthreads();
    if (tid == 0) {                            // exclusive scan of 16 wave totals
        int run = 0;
#pragma unroll
        for (int w = 0; w < SC_WAVES; ++w) { int t = wsum[w]; wsum[w] = run; run += t; }
    }
    __syncthreads();
    int prefix = (s - sown) + wsum[wid];
    for (int i = lo; i < hi; ++i) {
        int c = hist[i];
        binbase[i] = prefix;
        prefix += c;
        hist[i] = (c > 0) ? atomicAdd(&cursor[i], c) : 0;   // hist -> gbase
    }
    __syncthreads();

    // Phase 3 — stage records at sorted positions (pure compute, no re-read).
#pragma unroll
    for (int j = 0; j < SC_EPT; ++j) {
        if (rp[j] < 0) continue;
        int bkt  = rp[j] >> 19;
        int drow = (rp[j] >> 14) & (RB - 1);
        int rank = rp[j] & 16383;
        int pos = binbase[bkt] + rank;
        srec[pos] = ((u64)__float_as_uint(vv[j]) << 32) | ((u64)(uint)sv[j] << 6) | (u64)drow;
        bkts[pos] = (unsigned short)bkt;
    }
    __syncthreads();

    // Phase 4 — sorted, mostly-contiguous global writes.
    long long rem = E - base_e;
    int total = rem < SC_EDGES ? (int)rem : SC_EDGES;
    for (int i = tid; i < total; i += SC_BLOCK) {
        int bkt   = bkts[i];
        int lrank = i - binbase[bkt];
        int off   = hist[bkt] + lrank;
        if (off < CAP) packed[(size_t)bkt * CAP + off] = srec[i];
    }
}

// K3: atomic-free reduce, 512 threads = 16 slots x 32 batches.
// Stage+rank -> scatter full records into row-sorted LDS (no perm) ->
// each slot register-accumulates 2 rows' contiguous ranges -> transposed
// coalesced store with bias.
#define RD_BLOCK 512
__global__ __launch_bounds__(RD_BLOCK)
void SL_sort_reduce_kernel(const u64* __restrict__ packed, const int* __restrict__ cursor,
                           const __hip_bfloat16* __restrict__ xt,
                           const float* __restrict__ bias,
                           float* __restrict__ out, int M, int CAP) {
    __shared__ u64 ssort[SREC_MAX];
    __shared__ int bins[RB + 1];
    __shared__ float acc[RB][33];

    const int tid  = threadIdx.x;
    const int bkt  = blockIdx.x;
    const int row0 = bkt << RB_SHIFT;
    int nE = cursor[bkt];
    if (nE > CAP) nE = CAP;
    const u64* pb = packed + (size_t)bkt * CAP;

    if (tid < RB + 1) bins[tid] = 0;
    __syncthreads();

    // Stage to registers (coalesced) + per-row rank via 32-bin LDS histogram.
    u64 pr[SREC_MAX / RD_BLOCK];
    int rk[SREC_MAX / RD_BLOCK];
    int rw[SREC_MAX / RD_BLOCK];
#pragma unroll
    for (int i = 0; i < SREC_MAX / RD_BLOCK; ++i) {
        int k = tid + i * RD_BLOCK;
        rk[i] = -1; rw[i] = 0; pr[i] = 0;
        if (k < nE) {
            u64 r = pb[k];
            pr[i] = r;
            rw[i] = (int)(r & (RB - 1));
            rk[i] = atomicAdd(&bins[rw[i] + 1], 1);
        }
    }
    __syncthreads();

    // Exclusive prefix over 32 bins (serial, trivial): bins[r] = start of row r.
    if (tid == 0) {
#pragma unroll
        for (int r = 1; r <= RB; ++r) bins[r] += bins[r - 1];
    }
    __syncthreads();

    // Scatter full records into row-sorted order.
#pragma unroll
    for (int i = 0; i < SREC_MAX / RD_BLOCK; ++i) {
        if (rk[i] >= 0) ssort[bins[rw[i]] + rk[i]] = pr[i];
    }
    __syncthreads();

    // Register accumulation: slot s owns rows 2s..2s+1; lane b owns batch b.
    const int slot = tid >> 5;   // 0..15
    const int b    = tid & 31;
#pragma unroll
    for (int rr = 0; rr < 2; ++rr) {
        const int r  = slot * 2 + rr;
        const int j0 = bins[r];
        const int j1 = bins[r + 1];
        float a0 = 0.0f, a1 = 0.0f, a2 = 0.0f, a3 = 0.0f;
        int j = j0;
        for (; j + 4 <= j1; j += 4) {
            u64 p0 = ssort[j], p1 = ssort[j + 1], p2 = ssort[j + 2], p3 = ssort[j + 3];
            float x0 = __bfloat162float(xt[(size_t)((p0 >> 6) & 0x3FFFFFFu) * 32 + b]);
            float x1 = __bfloat162float(xt[(size_t)((p1 >> 6) & 0x3FFFFFFu) * 32 + b]);
            float x2 = __bfloat162float(xt[(size_t)((p2 >> 6) & 0x3FFFFFFu) * 32 + b]);
            float x3 = __bfloat162float(xt[(size_t)((p3 >> 6) & 0x3FFFFFFu) * 32 + b]);
            a0 += __uint_as_float((uint32_t)(p0 >> 32)) * x0;
            a1 += __uint_as_float((uint32_t)(p1 >> 32)) * x1;
            a2 += __uint_as_float((uint32_t)(p2 >> 32)) * x2;
            a3 += __uint_as_float((uint32_t)(p3 >> 32)) * x3;
        }
        for (; j < j1; ++j) {
            u64 p = ssort[j];
            float xv = __bfloat162float(xt[(size_t)((p >> 6) & 0x3FFFFFFu) * 32 + b]);
            a0 += __uint_as_float((uint32_t)(p >> 32)) * xv;
        }
        acc[r][b] = (a0 + a1) + (a2 + a3);   // unique (r,b) owner: plain write
    }
    __syncthreads();

    // out[b, row0+r] = acc[r][b] + bias[row0+r]; consecutive tid -> consecutive r.
    for (int i = tid; i < RB * 32; i += RD_BLOCK) {
        int rr = i & (RB - 1);
        int bb = i >> RB_SHIFT;
        int m  = row0 + rr;
        if (m < M)
            __builtin_nontemporal_store(acc[rr][bb] + bias[m], &out[(size_t)bb * M + m]);
    }
}

// K3 fallback (CAP > SREC_MAX): atomic bucket reduce (R5 structure).
#define RD_K 8
__global__ __launch_bounds__(256)
void SL_bucket_reduce_kernel(const u64* __restrict__ packed, const int* __restrict__ cursor,
                             const __hip_bfloat16* __restrict__ xt,
                             const float* __restrict__ bias,
                             float* __restrict__ out, int M, int CAP) {
    __shared__ float acc[RB][33];
    const int tid = threadIdx.x;
    for (int i = tid; i < RB * 33; i += 256) ((float*)acc)[i] = 0.0f;
    __syncthreads();

    const int bkt  = blockIdx.x;
    const int row0 = bkt << RB_SHIFT;
    int nE = cursor[bkt];
    if (nE > CAP) nE = CAP;
    const u64* pb = packed + (size_t)bkt * CAP;

    const int slot = tid >> 5;
    const int b    = tid & 31;

    for (int base = slot * RD_K; base < nE; base += 8 * RD_K) {
        u64 p[RD_K];
#pragma unroll
        for (int j = 0; j < RD_K; ++j) {
            int k = base + j;
            p[j] = (k < nE) ? pb[k] : 0ULL;
        }
        float xv[RD_K];
#pragma unroll
        for (int j = 0; j < RD_K; ++j) {
            int s = (int)((p[j] >> 6) & 0x3FFFFFFu);
            xv[j] = __bfloat162float(xt[(size_t)s * 32 + b]);
        }
#pragma unroll
        for (int j = 0; j < RD_K; ++j) {
            float v = __uint_as_float((uint32_t)(p[j] >> 32));
            atomicAdd(&acc[(int)(p[j] & (RB - 1))][b], v * xv[j]);
        }
    }
    __syncthreads();

    for (int i = tid; i < RB * 32; i += 256) {
        int rr = i & (RB - 1);
        int bb = i >> RB_SHIFT;
        int m  = row0 + rr;
        if (m < M)
            __builtin_nontemporal_store(acc[rr][bb] + bias[m], &out[(size_t)bb * M + m]);
    }
}

// ----------------- tier-2 fallback: direct atomic scatter ------------------

__global__ void SL_zero_kernel(int* __restrict__ p, long long n) {
    long long tid = (long long)blockIdx.x * blockDim.x + threadIdx.x;
    if (tid < n) p[tid] = 0;
}

__global__ void SL_convert_kernel(const int* __restrict__ raw, int* __restrict__ out,
                                  long long n, const int* __restrict__ flag) {
    long long tid = (long long)blockIdx.x * blockDim.x + threadIdx.x;
    if (tid >= n) return;
    const int is64 = *flag;
    out[tid] = is64 ? raw[tid * 2] : raw[tid];
}

__global__ void SL_prep_flat_kernel(const float* __restrict__ x, float* __restrict__ xt, int N) {
    long long tid = (long long)blockIdx.x * blockDim.x + threadIdx.x;
    long long totalN = (long long)N * 32;
    if (tid >= totalN) return;
    int n = (int)(tid >> 5);
    int b = (int)(tid & 31);
    xt[tid] = x[(long long)b * N + n];
}

__global__ void SL_scatter_kernel(const int* __restrict__ src, const int* __restrict__ dst,
                                  const float* __restrict__ vals, const float* __restrict__ xt,
                                  float* __restrict__ out_t, long long E) {
    long long tid = (long long)blockIdx.x * blockDim.x + threadIdx.x;
    long long e = tid >> 3;
    if (e >= E) return;
    int b0 = (int)(tid & 7) * 4;
    int s = src[e];
    int d = dst[e];
    float v = vals[e];
    const float4 xv = *reinterpret_cast<const float4*>(xt + (long long)s * 32 + b0);
    float* op = out_t + (long long)d * 32 + b0;
#if defined(__HIP_DEVICE_COMPILE__)
    unsafeAtomicAdd(op + 0, v * xv.x);
    unsafeAtomicAdd(op + 1, v * xv.y);
    unsafeAtomicAdd(op + 2, v * xv.z);
    unsafeAtomicAdd(op + 3, v * xv.w);
#endif
}

__global__ void SL_finalize_kernel(const float* __restrict__ out_t, const float* __restrict__ bias,
                                   float* __restrict__ out, int M) {
    __shared__ float tile[32][33];
    int m0 = blockIdx.x * 32;
    int tx = threadIdx.x;
    int ty = threadIdx.y;
    int m = m0 + ty;
    if (m < M) tile[ty][tx] = out_t[(long long)m * 32 + tx];
    __syncthreads();
    int mm = m0 + tx;
    if (mm < M) out[(long long)ty * M + mm] = tile[tx][ty] + bias[mm];
}

// ----------------- tier-3 fallback: fully generic ------------------

__global__ void SL_init_out_kernel(const float* __restrict__ bias, float* __restrict__ out,
                                   int M, long long total) {
    long long tid = (long long)blockIdx.x * blockDim.x + threadIdx.x;
    if (tid < total) out[tid] = bias[tid % M];
}

__global__ void SL_scatter_direct_kernel(const int* __restrict__ raw, const int* __restrict__ flag,
                                         const float* __restrict__ vals, const float* __restrict__ x,
                                         float* __restrict__ out, long long E, int N, int M, int B) {
    long long e = (long long)blockIdx.x * blockDim.x + threadIdx.x;
    if (e >= E) return;
    const int is64 = *flag;
    long long s = is64 ? raw[2 * e] : raw[e];
    long long d = is64 ? raw[2 * (E + e)] : raw[E + e];
    float v = vals[e];
    for (int b = 0; b < B; ++b) {
#if defined(__HIP_DEVICE_COMPILE__)
        unsafeAtomicAdd(&out[(long long)b * M + d], v * x[(long long)b * N + s]);
#endif
    }
}

extern "C" void kernel_launch(void* const* d_in, const int* in_sizes, int n_in,
                              void* d_out, int out_size, void* d_ws, size_t ws_size,
                              hipStream_t stream) {
    const float* x       = (const float*)d_in[0];
    const int*   idx_raw = (const int*)d_in[1];
    const float* vals    = (const float*)d_in[2];
    const float* bias    = (const float*)d_in[3];
    float*       out     = (float*)d_out;

    const long long twoE = in_sizes[1];
    const long long E    = twoE / 2;
    const int M = in_sizes[3];
    const int B = out_size / M;
    const int N = in_sizes[0] / B;

    const int NB = (M + RB - 1) >> RB_SHIFT;
    double mean = (double)E / (double)NB;
    int CAP = (int)(mean + 8.0 * sqrt(mean > 1.0 ? mean : 1.0) + 128.0);
    CAP = (CAP + 63) & ~63;

    const size_t xt_b  = (((size_t)N * 32 * sizeof(__hip_bfloat16)) + 255) & ~(size_t)255;
    const size_t pk_b  = (size_t)NB * (size_t)CAP * sizeof(u64);
    const size_t need1 = xt_b + pk_b + (size_t)NB * 4 + 64;
    const size_t need2 = ((size_t)(N + M) * 32 + (size_t)twoE + 1) * sizeof(int);

    // Scatter dynamic LDS: hist + binbase (NB ints each) + wsum (16 ints)
    // + bkts (SC_EDGES u16) + srec (SC_EDGES u64).
    const size_t sc_lds = (size_t)(2 * NB + 16) * 4
                        + (size_t)SC_EDGES * 2 + (size_t)SC_EDGES * 8;

    if (B == 32 && N <= (1 << 26) && NB <= 2047 && ws_size >= need1 && sc_lds <= 64 * 1024) {
        char* ws = (char*)d_ws;
        __hip_bfloat16* xt = (__hip_bfloat16*)ws;
        u64* packed = (u64*)(ws + xt_b);
        int* cursor = (int*)(ws + xt_b + pk_b);
        int* flag   = cursor + NB;

        SL_detect_zero_kernel<<<(NB + 255) / 256, 256, 0, stream>>>(
            (const uint32_t*)idx_raw, flag, cursor, NB);

        dim3 pblk(32, 32);
        SL_prep_kernel<<<(N + 31) / 32, pblk, 0, stream>>>(x, xt, N);

        unsigned sgrid = (unsigned)((E + SC_EDGES - 1) / SC_EDGES);
        SL_bucket_scatter_kernel<<<sgrid, SC_BLOCK, (unsigned)sc_lds, stream>>>(
            idx_raw, flag, vals, packed, cursor, E, NB, CAP);

        if (CAP <= SREC_MAX) {
            SL_sort_reduce_kernel<<<NB, RD_BLOCK, 0, stream>>>(
                packed, cursor, xt, bias, out, M, CAP);
        } else {
            SL_bucket_reduce_kernel<<<NB, 256, 0, stream>>>(
                packed, cursor, xt, bias, out, M, CAP);
        }
    } else if (B == 32 && ws_size >= need2) {
        float* xtf   = (float*)d_ws;
        float* out_t = xtf + (size_t)N * 32;
        int*   idx32 = (int*)(out_t + (size_t)M * 32);
        int*   flag  = idx32 + twoE;

        SL_detect_zero_kernel<<<1, 256, 0, stream>>>((const uint32_t*)idx_raw, flag, flag, 0);
        SL_convert_kernel<<<(unsigned)((twoE + 255) / 256), 256, 0, stream>>>(
            idx_raw, idx32, twoE, flag);
        long long prep_total = (long long)N * 32;
        SL_prep_flat_kernel<<<(unsigned)((prep_total + 255) / 256), 256, 0, stream>>>(x, xtf, N);
        SL_zero_kernel<<<(unsigned)(((long long)M * 32 + 255) / 256), 256, 0, stream>>>(
            (int*)out_t, (long long)M * 32);
        long long sc_total = E * 8;
        SL_scatter_kernel<<<(unsigned)((sc_total + 255) / 256), 256, 0, stream>>>(
            idx32, idx32 + E, vals, xtf, out_t, E);
        dim3 blk(32, 32);
        SL_finalize_kernel<<<(M + 31) / 32, blk, 0, stream>>>(out_t, bias, out, M);
    } else if (ws_size >= sizeof(int)) {
        int* flag = (int*)d_ws;
        SL_detect_zero_kernel<<<1, 256, 0, stream>>>((const uint32_t*)idx_raw, flag, flag, 0);
        long long total = (long long)B * M;
        SL_init_out_kernel<<<(unsigned)((total + 255) / 256), 256, 0, stream>>>(bias, out, M, total);
        SL_scatter_direct_kernel<<<(unsigned)((E + 255) / 256), 256, 0, stream>>>(
            idx_raw, flag, vals, x, out, E, N, M, B);
    }
}